// Round 8
// baseline (11058.685 us; speedup 1.0000x reference)
//
#include <hip/hip_runtime.h>

typedef unsigned short u16;
typedef _Float16 f16_t;
typedef f16_t f16x8 __attribute__((ext_vector_type(8)));
typedef float f32x4 __attribute__((ext_vector_type(4)));

#define T_STEPS 256
#define IN_DIM  5
#define ROWS    64      // batch rows per 4-CU group
#define NBLK    256

// d_ws byte layout:
//   WS_W    @ 0       : weight frags [16 slice][100 frag][64 lane][16B] = 1,638,400
//   WS_BIAS @ 1638400 : f32 bias0[1024], bias1[1024]
//   WS_GX   @ 1646592 : u16 gx0[2 parity][64 grp][64 row][256 col]  (2 x 2 MB)
//                       u16 gx1[2 parity][64 grp][64 row][256 col]  (2 x 2 MB)
//   WS_CNT  @ 10035200: u32 cnt0[1024], cnt1[1024] (zeroed each launch by prep)
#define WS_BIAS 1638400
#define WS_GX   1646592
#define GXBUF   1048576                 // u16 elements per parity buffer (2 MB)
#define WS_CNT  (WS_GX + 4 * 2097152)   // 10,035,200

__device__ __forceinline__ float sigf(float x)  { return 1.0f / (1.0f + __expf(-x)); }
__device__ __forceinline__ float tanh_f(float x){ return 1.0f - 2.0f / (__expf(2.0f * x) + 1.0f); }

__global__ void prep_kernel(const float* __restrict__ wih0, const float* __restrict__ whh0,
                            const float* __restrict__ wih1, const float* __restrict__ whh1,
                            const float* __restrict__ bih0, const float* __restrict__ bhh0,
                            const float* __restrict__ bih1, const float* __restrict__ bhh1,
                            u16* __restrict__ wsw, float* __restrict__ biases,
                            unsigned* __restrict__ cnt)
{
    int j = blockIdx.x * blockDim.x + threadIdx.x;
    if (j < 102400) {
        // j = (slice*100 + f)*64 + lane ; slice = sub*4 + wv
        int slice = j / 6400;
        int rem   = j - slice * 6400;
        int f     = rem >> 6;
        int lane  = rem & 63;
        int sub = slice >> 2, wv = slice & 3;
        int lrow = lane & 15;
        int kp = (lane >> 4) * 8;
        u16 tmp[8];
#pragma unroll
        for (int e = 0; e < 8; ++e) {
            int k = kp + e;
            float v;
            if (f < 36) {                              // GEMM0: gi*9 + ks (ks==8 -> w_ih0 pad)
                int gi = f / 9, ks = f - gi * 9;
                int grow = gi * 256 + sub * 64 + wv * 16 + lrow;
                v = (ks < 8) ? whh0[grow * 256 + ks * 32 + k]
                             : (k < IN_DIM ? wih0[grow * IN_DIM + k] : 0.0f);
            } else {                                   // GEMM1: 36 + gi*16 + ks (0-7 ih1, 8-15 hh1)
                int ff = f - 36;
                int gi = ff >> 4, ks = ff & 15;
                int grow = gi * 256 + sub * 64 + wv * 16 + lrow;
                v = (ks < 8) ? wih1[grow * 256 + ks * 32 + k]
                             : whh1[grow * 256 + (ks - 8) * 32 + k];
            }
            tmp[e] = __builtin_bit_cast(u16, (f16_t)v);
        }
        *(uint4*)(wsw + (size_t)j * 8) = *(uint4*)tmp;
    } else if (j < 103424) {
        int i = j - 102400;
        biases[i] = bih0[i] + bhh0[i];
    } else if (j < 104448) {
        int i = j - 103424;
        biases[1024 + i] = bih1[i] + bhh1[i];
    } else if (j < 106496) {
        cnt[j - 104448] = 0u;                          // monotone sync counters
    }
}

__global__ __launch_bounds__(256, 1) void lstm_fused(
    const float* __restrict__ x, const u16* __restrict__ wsw,
    const float* __restrict__ biases, const float* __restrict__ fcw_g,
    const float* __restrict__ fcb_g, float* __restrict__ out,
    u16* __restrict__ gxbase, unsigned* __restrict__ cnt)
{
    extern __shared__ char smem[];
    char* h0base = smem;               // [2][64 rows][512B] fp16, XOR-swizzled
    char* h1base = smem + 65536;       // [64][512B]  (single buffer, per-mt barrier)
    char* cstb   = smem + 98304;       // c-state: [2 layer][4 wv][4 mt][64 lane][16B]
    char* xbb    = smem + 131072;      // [64 rows][64B] x_t staged (zero-padded)

    const int tid  = threadIdx.x;
    const int wv   = tid >> 6;         // wave 0..3: owns hidden cols [sub*64+wv*16, +16), all 4 gates
    const int lane = tid & 63;
    const int lrow = lane & 15;
    const int lkg  = lane >> 4;
    const int sub  = blockIdx.x >> 6;  // CU index within group (0..3)
    const int grp  = blockIdx.x & 63;  // group; members {g, g+64, g+128, g+192}
    const int r0   = grp * ROWS;
    const int aswz = (lrow & 7) << 4;
    const int xswz = (lrow & 3) << 4;

    // ---- resident weight shard: 100 f16x8 frags = 400 AGPRs/lane.
    // Load + launder ONE fragment at a time, with sched_barrier(0) fences so
    // the machine scheduler cannot batch the loads: arch-VGPR pressure during
    // init stays ~8, letting the allocator pick a small accum_offset (~112)
    // so all 400 AGPRs exist. (R7's bulk-load version ballooned arch demand
    // to 256 -> only 256 AGPRs -> ~144 frags/wave silently re-streamed.)
    f16x8 w0[4][9], w1g[4][16];
    const u16* wbase = wsw + (size_t)(sub * 4 + wv) * 51200;
#pragma unroll
    for (int gi = 0; gi < 4; ++gi)
#pragma unroll
        for (int ks = 0; ks < 9; ++ks) {
            w0[gi][ks] = *(const f16x8*)(wbase + (gi * 9 + ks) * 512 + lane * 8);
            asm volatile("" : "+a"(w0[gi][ks]));
            __builtin_amdgcn_sched_barrier(0);
        }
#pragma unroll
    for (int gi = 0; gi < 4; ++gi)
#pragma unroll
        for (int ks = 0; ks < 16; ++ks) {
            w1g[gi][ks] = *(const f16x8*)(wbase + (36 + gi * 16 + ks) * 512 + lane * 8);
            asm volatile("" : "+a"(w1g[gi][ks]));
            __builtin_amdgcn_sched_barrier(0);
        }

    float bi0[4], bi1[4];
#pragma unroll
    for (int gi = 0; gi < 4; ++gi) {
        int gcol = gi * 256 + sub * 64 + wv * 16 + lrow;
        bi0[gi] = biases[gcol];
        bi1[gi] = biases[1024 + gcol];
    }
    float fcw[4];
#pragma unroll
    for (int r = 0; r < 4; ++r) fcw[r] = fcw_g[lane * 4 + r];
    const float fcb = fcb_g[0];

    unsigned* c0p = cnt + grp * 16;
    unsigned* c1p = cnt + 1024 + grp * 16;

    // zero all LDS (h0 both bufs, h1, c-state, xb pads)
    for (int i = tid; i < 135168 / 4; i += 256) ((unsigned*)smem)[i] = 0u;
    __syncthreads();
    // stage x_0 (320 = 64 rows x 5)
    {
        int ra = tid / 5, ka = tid - ra * 5;
        float v = x[((size_t)(r0 + ra) * T_STEPS + 0) * IN_DIM + ka];
        *(u16*)(xbb + ra * 64 + ((2 * ka) ^ ((ra & 3) << 4))) = __builtin_bit_cast(u16, (f16_t)v);
        if (tid < 64) {
            int idx = tid + 256, rb = idx / 5, kb = idx - rb * 5;
            float v2 = x[((size_t)(r0 + rb) * T_STEPS + 0) * IN_DIM + kb];
            *(u16*)(xbb + rb * 64 + ((2 * kb) ^ ((rb & 3) << 4))) = __builtin_bit_cast(u16, (f16_t)v2);
        }
    }
    __syncthreads();

#pragma unroll 1
    for (int t = 0; t < T_STEPS; ++t) {
        const int p = t & 1;
        const char* h0p = h0base + p * 32768;
        char* h0w = h0base + (p ^ 1) * 32768;
        u16* gx0w = gxbase + (size_t)p * GXBUF + grp * 16384;            // publish h0(t)
        u16* gx1w = gxbase + (size_t)(2 + p) * GXBUF + grp * 16384;      // publish h1(t)
        const u16* gx1r = gxbase + (size_t)(2 + (p ^ 1)) * GXBUF + grp * 16384; // read h1(t-1)

        // prefetch x_{t+1}
        float xv0 = 0.0f, xv1 = 0.0f;
        if (t + 1 < T_STEPS) {
            int ra = tid / 5, ka = tid - ra * 5;
            xv0 = x[((size_t)(r0 + ra) * T_STEPS + (t + 1)) * IN_DIM + ka];
            if (tid < 64) {
                int idx = tid + 256, rb = idx / 5, kb = idx - rb * 5;
                xv1 = x[((size_t)(r0 + rb) * T_STEPS + (t + 1)) * IN_DIM + kb];
            }
        }

        // ---- A: GEMM0 + epilogue0 per mtile; publish own h0 chunk ----
#pragma unroll
        for (int mt = 0; mt < 4; ++mt) {
            f32x4 acc[4] = {};
            const int arow = mt * 16 + lrow;
#pragma unroll
            for (int ks = 0; ks < 8; ++ks) {
                f16x8 a = *(const f16x8*)(h0p + arow * 512 + ((ks * 64 + lkg * 16) ^ aswz));
#pragma unroll
                for (int gi = 0; gi < 4; ++gi)
                    acc[gi] = __builtin_amdgcn_mfma_f32_16x16x32_f16(a, w0[gi][ks], acc[gi], 0, 0, 0);
            }
            {
                f16x8 a = *(const f16x8*)(xbb + arow * 64 + ((lkg * 16) ^ xswz));
#pragma unroll
                for (int gi = 0; gi < 4; ++gi)
                    acc[gi] = __builtin_amdgcn_mfma_f32_16x16x32_f16(a, w0[gi][8], acc[gi], 0, 0, 0);
            }
            char* cp = cstb + ((wv * 4 + mt) * 64 + lane) * 16;
            f32x4 cold = *(f32x4*)cp, cnew;
#pragma unroll
            for (int r = 0; r < 4; ++r) {
                float ig = acc[0][r] + bi0[0];
                float fg = acc[1][r] + bi0[1];
                float gg = acc[2][r] + bi0[2];
                float og = acc[3][r] + bi0[3];
                float c  = sigf(fg) * cold[r] + sigf(ig) * tanh_f(gg);
                cnew[r] = c;
                u16 hb = __builtin_bit_cast(u16, (f16_t)(sigf(og) * tanh_f(c)));
                int row = mt * 16 + lkg * 4 + r;
                int col = sub * 64 + wv * 16 + lrow;
                *(u16*)(h0w + row * 512 + ((col * 2) ^ ((row & 7) << 4))) = hb;
                gx0w[row * 256 + col] = hb;
            }
            *(f32x4*)cp = cnew;
        }
        __syncthreads();                      // all waves' gx0 stores retired (vmcnt drain)
        if (tid == 0)
            __hip_atomic_fetch_add(c0p, 1u, __ATOMIC_RELEASE, __HIP_MEMORY_SCOPE_AGENT);

        // ---- B: finalize h1(t-1): spin c1, assemble remote chunks, FC(t-1);
        //         stage x_{t+1}. (covers the h1 exchange; GEMM0 above covered it too)
        if (t > 0 && tid == 0) {
            const unsigned tgt = 4u * (unsigned)t;
            while (__hip_atomic_load(c1p, __ATOMIC_ACQUIRE, __HIP_MEMORY_SCOPE_AGENT) < tgt)
                __builtin_amdgcn_s_sleep(2);
        }
        __syncthreads();
        {
            if (t > 0) {
                int row = tid >> 2, q = tid & 3;
#pragma unroll
                for (int so = 1; so < 4; ++so) {
                    int s2 = (sub + so) & 3;
                    const u16* src = gx1r + row * 256 + s2 * 64 + q * 16;
                    uint4 v0 = *(const uint4*)src;
                    uint4 v1 = *(const uint4*)(src + 8);
                    int cb = (s2 * 64 + q * 16) * 2;
                    int sw = (row & 7) << 4;
                    *(uint4*)(h1base + row * 512 + (cb ^ sw)) = v0;
                    *(uint4*)(h1base + row * 512 + ((cb + 16) ^ sw)) = v1;
                }
            }
            if (t + 1 < T_STEPS) {
                int ra = tid / 5, ka = tid - ra * 5;
                *(u16*)(xbb + ra * 64 + ((2 * ka) ^ ((ra & 3) << 4))) = __builtin_bit_cast(u16, (f16_t)xv0);
                if (tid < 64) {
                    int idx = tid + 256, rb = idx / 5, kb = idx - rb * 5;
                    *(u16*)(xbb + rb * 64 + ((2 * kb) ^ ((rb & 3) << 4))) = __builtin_bit_cast(u16, (f16_t)xv1);
                }
            }
        }
        __syncthreads();
        if (t > 0) {                          // deferred FC on h1(t-1), now complete
#pragma unroll
            for (int rr = 0; rr < 4; ++rr) {
                int row = sub * 16 + wv * 4 + rr;
                uint2 raw = *(const uint2*)(h1base + row * 512 + ((lane * 8) ^ ((row & 7) << 4)));
                float s = (float)__builtin_bit_cast(f16_t, (u16)(raw.x & 0xffff)) * fcw[0]
                        + (float)__builtin_bit_cast(f16_t, (u16)(raw.x >> 16))    * fcw[1]
                        + (float)__builtin_bit_cast(f16_t, (u16)(raw.y & 0xffff)) * fcw[2]
                        + (float)__builtin_bit_cast(f16_t, (u16)(raw.y >> 16))    * fcw[3];
#pragma unroll
                for (int off = 32; off > 0; off >>= 1) s += __shfl_xor(s, off);
                if (lane == 0) out[(size_t)(r0 + row) * T_STEPS + (t - 1)] = s + fcb;
            }
        }

        // ---- D: h0(t) exchange completes (spin covered by B above) ----
        if (tid == 0) {
            const unsigned tgt = 4u * (unsigned)(t + 1);
            while (__hip_atomic_load(c0p, __ATOMIC_ACQUIRE, __HIP_MEMORY_SCOPE_AGENT) < tgt)
                __builtin_amdgcn_s_sleep(2);
        }
        __syncthreads();
        {
            int row = tid >> 2, q = tid & 3;
            const u16* gx0r = gx0w - (size_t)grp * 16384 + (size_t)grp * 16384; // same buffer
#pragma unroll
            for (int so = 1; so < 4; ++so) {
                int s2 = (sub + so) & 3;
                const u16* src = gx0w + row * 256 + s2 * 64 + q * 16;
                uint4 v0 = *(const uint4*)src;
                uint4 v1 = *(const uint4*)(src + 8);
                int cb = (s2 * 64 + q * 16) * 2;
                int sw = (row & 7) << 4;
                *(uint4*)(h0w + row * 512 + (cb ^ sw)) = v0;
                *(uint4*)(h0w + row * 512 + ((cb + 16) ^ sw)) = v1;
            }
        }
        __syncthreads();

        // ---- E: GEMM1 + epilogue1 per mtile (acc transient per mt);
        //         per-mt barrier separates h1(t-1) reads from h1(t) writes ----
#pragma unroll
        for (int mt = 0; mt < 4; ++mt) {
            f32x4 acc[4] = {};
            const int arow = mt * 16 + lrow;
#pragma unroll
            for (int ks = 0; ks < 8; ++ks) {
                f16x8 a = *(const f16x8*)(h0w + arow * 512 + ((ks * 64 + lkg * 16) ^ aswz));
#pragma unroll
                for (int gi = 0; gi < 4; ++gi)
                    acc[gi] = __builtin_amdgcn_mfma_f32_16x16x32_f16(a, w1g[gi][ks], acc[gi], 0, 0, 0);
            }
#pragma unroll
            for (int ks = 8; ks < 16; ++ks) {
                f16x8 a = *(const f16x8*)(h1base + arow * 512 + (((ks - 8) * 64 + lkg * 16) ^ aswz));
#pragma unroll
                for (int gi = 0; gi < 4; ++gi)
                    acc[gi] = __builtin_amdgcn_mfma_f32_16x16x32_f16(a, w1g[gi][ks], acc[gi], 0, 0, 0);
            }
            __syncthreads();   // all waves done reading this mt's h1(t-1) rows
            char* cp = cstb + 16384 + ((wv * 4 + mt) * 64 + lane) * 16;
            f32x4 cold = *(f32x4*)cp, cnew;
#pragma unroll
            for (int r = 0; r < 4; ++r) {
                float ig = acc[0][r] + bi1[0];
                float fg = acc[1][r] + bi1[1];
                float gg = acc[2][r] + bi1[2];
                float og = acc[3][r] + bi1[3];
                float c  = sigf(fg) * cold[r] + sigf(ig) * tanh_f(gg);
                cnew[r] = c;
                u16 hb = __builtin_bit_cast(u16, (f16_t)(sigf(og) * tanh_f(c)));
                int row = mt * 16 + lkg * 4 + r;
                int col = sub * 64 + wv * 16 + lrow;
                *(u16*)(h1base + row * 512 + ((col * 2) ^ ((row & 7) << 4))) = hb;
                gx1w[row * 256 + col] = hb;
            }
            *(f32x4*)cp = cnew;
        }
        __syncthreads();                      // all waves' gx1 stores retired
        if (tid == 0)
            __hip_atomic_fetch_add(c1p, 1u, __ATOMIC_RELEASE, __HIP_MEMORY_SCOPE_AGENT);
    }

    // ---- loop epilogue: finalize h1(T-1) and emit FC(T-1) ----
    if (tid == 0) {
        const unsigned tgt = 4u * (unsigned)T_STEPS;
        while (__hip_atomic_load(c1p, __ATOMIC_ACQUIRE, __HIP_MEMORY_SCOPE_AGENT) < tgt)
            __builtin_amdgcn_s_sleep(2);
    }
    __syncthreads();
    {
        const u16* gx1r = gxbase + (size_t)(2 + ((T_STEPS - 1) & 1)) * GXBUF + grp * 16384;
        int row = tid >> 2, q = tid & 3;
#pragma unroll
        for (int so = 1; so < 4; ++so) {
            int s2 = (sub + so) & 3;
            const u16* src = gx1r + row * 256 + s2 * 64 + q * 16;
            uint4 v0 = *(const uint4*)src;
            uint4 v1 = *(const uint4*)(src + 8);
            int cb = (s2 * 64 + q * 16) * 2;
            int sw = (row & 7) << 4;
            *(uint4*)(h1base + row * 512 + (cb ^ sw)) = v0;
            *(uint4*)(h1base + row * 512 + ((cb + 16) ^ sw)) = v1;
        }
    }
    __syncthreads();
#pragma unroll
    for (int rr = 0; rr < 4; ++rr) {
        int row = sub * 16 + wv * 4 + rr;
        uint2 raw = *(const uint2*)(h1base + row * 512 + ((lane * 8) ^ ((row & 7) << 4)));
        float s = (float)__builtin_bit_cast(f16_t, (u16)(raw.x & 0xffff)) * fcw[0]
                + (float)__builtin_bit_cast(f16_t, (u16)(raw.x >> 16))    * fcw[1]
                + (float)__builtin_bit_cast(f16_t, (u16)(raw.y & 0xffff)) * fcw[2]
                + (float)__builtin_bit_cast(f16_t, (u16)(raw.y >> 16))    * fcw[3];
#pragma unroll
        for (int off = 32; off > 0; off >>= 1) s += __shfl_xor(s, off);
        if (lane == 0) out[(size_t)(r0 + row) * T_STEPS + (T_STEPS - 1)] = s + fcb;
    }
}

extern "C" void kernel_launch(void* const* d_in, const int* in_sizes, int n_in,
                              void* d_out, int out_size, void* d_ws, size_t ws_size,
                              hipStream_t stream)
{
    const float* x    = (const float*)d_in[0];
    const float* wih0 = (const float*)d_in[1];
    const float* whh0 = (const float*)d_in[2];
    const float* bih0 = (const float*)d_in[3];
    const float* bhh0 = (const float*)d_in[4];
    const float* wih1 = (const float*)d_in[5];
    const float* whh1 = (const float*)d_in[6];
    const float* bih1 = (const float*)d_in[7];
    const float* bhh1 = (const float*)d_in[8];
    const float* fcw  = (const float*)d_in[9];
    const float* fcb  = (const float*)d_in[10];

    u16* wsw      = (u16*)d_ws;
    float* biases = (float*)((char*)d_ws + WS_BIAS);
    u16* gxbase   = (u16*)((char*)d_ws + WS_GX);
    unsigned* cnt = (unsigned*)((char*)d_ws + WS_CNT);

    prep_kernel<<<416, 256, 0, stream>>>(wih0, whh0, wih1, whh1,
                                         bih0, bhh0, bih1, bhh1, wsw, biases, cnt);
    lstm_fused<<<NBLK, 256, 135168, stream>>>(x, wsw, biases, fcw, fcb,
                                              (float*)d_out, gxbase, cnt);
}

// Round 9
// 9884.049 us; speedup vs baseline: 1.1188x; 1.1188x over previous
//
#include <hip/hip_runtime.h>

typedef unsigned short u16;
typedef _Float16 f16_t;
typedef f16_t f16x8 __attribute__((ext_vector_type(8)));
typedef float f32x4 __attribute__((ext_vector_type(4)));

#define T_STEPS 256
#define IN_DIM  5
#define GROWS   128     // batch rows per 8-CU group
#define NBLK    256

// d_ws byte layout:
//   WS_W    @ 0       : weight frags [32 slice][50 frag][64 lane][16B] = 1,638,400
//   WS_BIAS @ 1638400 : f32 bias0[1024], bias1[1024]
//   WS_GX   @ 1646592 : u16 gx0[2 parity][32 grp][8 sub][128 row][32 col] (2 x 2 MB)
//                       u16 gx1[2 parity][...]                            (2 x 2 MB)
//   WS_CNT  @ 10035200: u32 cnt0[1024], cnt1[1024] (zeroed each launch by prep)
#define WS_BIAS 1638400
#define WS_GX   1646592
#define GXBUF   1048576                 // u16 elements per parity buffer (2 MB)
#define WS_CNT  (WS_GX + 4 * 2097152)

__device__ __forceinline__ float sigf(float x)  { return 1.0f / (1.0f + __expf(-x)); }
__device__ __forceinline__ float tanh_f(float x){ return 1.0f - 2.0f / (__expf(2.0f * x) + 1.0f); }

__global__ void prep_kernel(const float* __restrict__ wih0, const float* __restrict__ whh0,
                            const float* __restrict__ wih1, const float* __restrict__ whh1,
                            const float* __restrict__ bih0, const float* __restrict__ bhh0,
                            const float* __restrict__ bih1, const float* __restrict__ bhh1,
                            u16* __restrict__ wsw, float* __restrict__ biases,
                            unsigned* __restrict__ cnt)
{
    int j = blockIdx.x * blockDim.x + threadIdx.x;
    if (j < 102400) {
        // j = (slice*50 + f)*64 + lane ; slice = sub*4 + wv  (32 slices)
        int slice = j / 3200;
        int rem   = j - slice * 3200;
        int f     = rem >> 6;           // 0..49
        int lane  = rem & 63;
        int sub = slice >> 2, wv = slice & 3;
        int lrow = lane & 15;
        int kp = (lane >> 4) * 8;
        // gate-paired tiles: weight row = (nt*2 + hi)*256 + sub*32 + wv*8 + j
        int nt, ks; bool g0;
        if (f < 18) { g0 = true;  nt = f / 9;  ks = f - nt * 9; }
        else        { int ff = f - 18; g0 = false; nt = ff >> 4; ks = ff & 15; }
        int wr = (nt * 2 + (lrow >> 3)) * 256 + sub * 32 + wv * 8 + (lrow & 7);
        u16 tmp[8];
#pragma unroll
        for (int e = 0; e < 8; ++e) {
            int k = kp + e;
            float v;
            if (g0) {
                v = (ks < 8) ? whh0[wr * 256 + ks * 32 + k]
                             : (k < IN_DIM ? wih0[wr * IN_DIM + k] : 0.0f);
            } else {
                v = (ks < 8) ? wih1[wr * 256 + ks * 32 + k]
                             : whh1[wr * 256 + (ks - 8) * 32 + k];
            }
            tmp[e] = __builtin_bit_cast(u16, (f16_t)v);
        }
        *(uint4*)(wsw + (size_t)j * 8) = *(uint4*)tmp;
    } else if (j < 103424) {
        int i = j - 102400;
        biases[i] = bih0[i] + bhh0[i];
    } else if (j < 104448) {
        int i = j - 103424;
        biases[1024 + i] = bih1[i] + bhh1[i];
    } else if (j < 106496) {
        cnt[j - 104448] = 0u;
    }
}

__global__ __launch_bounds__(256, 1) void lstm_fused(
    const float* __restrict__ x, const u16* __restrict__ wsw,
    const float* __restrict__ biases, const float* __restrict__ fcw_g,
    const float* __restrict__ fcb_g, float* __restrict__ out,
    u16* __restrict__ gxbase, unsigned* __restrict__ cnt)
{
    extern __shared__ char smem[];
    char* h0b = smem;                  // [128 rows][512B] fp16, XOR-swizzled
    char* h1b = smem + 65536;          // [128 rows][512B]
    char* xbb = smem + 131072;         // [128 rows][64B] x_t staged (zero-padded)

    const int tid  = threadIdx.x;
    const int wv   = tid >> 6;         // wave 0..3: hidden cols sub*32 + wv*8 .. +8, all 4 gates
    const int lane = tid & 63;
    const int lrow = lane & 15;
    const int lkg  = lane >> 4;
    const int sub  = blockIdx.x >> 5;  // CU index within group (0..7)
    const int grp  = blockIdx.x & 31;  // group; members {g, g+32, ..., g+224} (same XCD)
    const int r0   = grp * GROWS;
    const int aswz = (lrow & 7) << 4;
    const int xswz = (lrow & 3) << 4;
    const bool lo  = (lrow < 8);

    // ---- resident weight shard: 50 f16x8 frags = 200 AGPRs/lane (<= 256 available).
    // Per-frag load + "+a" launder + sched_barrier keeps init pressure minimal and
    // makes rematerialization illegal. 200 <= 256 is the fix for R7/R8's overflow.
    f16x8 w0[2][9], w1[2][16];
    const u16* wbase = wsw + (size_t)(sub * 4 + wv) * 25600;
#pragma unroll
    for (int nt = 0; nt < 2; ++nt)
#pragma unroll
        for (int ks = 0; ks < 9; ++ks) {
            w0[nt][ks] = *(const f16x8*)(wbase + (nt * 9 + ks) * 512 + lane * 8);
            asm volatile("" : "+a"(w0[nt][ks]));
            __builtin_amdgcn_sched_barrier(0);
        }
#pragma unroll
    for (int nt = 0; nt < 2; ++nt)
#pragma unroll
        for (int ks = 0; ks < 16; ++ks) {
            w1[nt][ks] = *(const f16x8*)(wbase + (18 + nt * 16 + ks) * 512 + lane * 8);
            asm volatile("" : "+a"(w1[nt][ks]));
            __builtin_amdgcn_sched_barrier(0);
        }

    float b0[2], b1[2];
#pragma unroll
    for (int nt = 0; nt < 2; ++nt) {
        int wr = (nt * 2 + (lrow >> 3)) * 256 + sub * 32 + wv * 8 + (lrow & 7);
        b0[nt] = biases[wr];
        b1[nt] = biases[1024 + wr];
    }
    float fcw[4];
#pragma unroll
    for (int r = 0; r < 4; ++r) fcw[r] = fcw_g[lane * 4 + r];
    const float fcb = fcb_g[0];

    unsigned* c0p = cnt + grp * 16;
    unsigned* c1p = cnt + 1024 + grp * 16;

    // zero LDS (h0, h1, xbb incl pads)
    for (int i = tid; i < 139264 / 4; i += 256) ((unsigned*)smem)[i] = 0u;
    __syncthreads();
    // stage x_0
    for (int i = tid; i < GROWS * IN_DIM; i += 256) {
        int row = i / 5, k = i - row * 5;
        float v = x[((size_t)(r0 + row) * T_STEPS + 0) * IN_DIM + k];
        *(u16*)(xbb + row * 64 + ((2 * k) ^ ((row & 3) << 4))) = __builtin_bit_cast(u16, (f16_t)v);
    }
    __syncthreads();

    float c0[8][4] = {};   // c-state, wave-private, duplicated across lane halves
    float c1[8][4] = {};

#pragma unroll 1
    for (int t = 0; t < T_STEPS; ++t) {
        const int p = t & 1;
        u16* gx0w = gxbase + (size_t)p * GXBUF + (size_t)(grp * 8 + sub) * 4096;
        u16* gx1w = gxbase + (size_t)(2 + p) * GXBUF + (size_t)(grp * 8 + sub) * 4096;
        const u16* gx0r = gxbase + (size_t)p * GXBUF + (size_t)grp * 8 * 4096;
        const u16* gx1r = gxbase + (size_t)(2 + p) * GXBUF + (size_t)grp * 8 * 4096;

        // prefetch x(t+1) into regs (latency hides under GEMM0)
        float xv0 = 0.f, xv1 = 0.f, xv2 = 0.f;
        if (t + 1 < T_STEPS) {
            int i0 = tid, i1 = tid + 256, i2 = tid + 512;
            { int row = i0 / 5, k = i0 - row * 5;
              xv0 = x[((size_t)(r0 + row) * T_STEPS + (t + 1)) * IN_DIM + k]; }
            { int row = i1 / 5, k = i1 - row * 5;
              xv1 = x[((size_t)(r0 + row) * T_STEPS + (t + 1)) * IN_DIM + k]; }
            if (i2 < GROWS * IN_DIM) {
                int row = i2 / 5, k = i2 - row * 5;
                xv2 = x[((size_t)(r0 + row) * T_STEPS + (t + 1)) * IN_DIM + k];
            }
        }

        // ---- GEMM0 + epilogue0: reads h0(t-1)+x(t) LDS; writes ONLY gx0 + c regs ----
#pragma unroll
        for (int mt = 0; mt < 8; ++mt) {
            f32x4 a0 = {}, a1 = {};
            const int arow = mt * 16 + lrow;
#pragma unroll
            for (int ks = 0; ks < 8; ++ks) {
                f16x8 a = *(const f16x8*)(h0b + arow * 512 + ((ks * 64 + lkg * 16) ^ aswz));
                a0 = __builtin_amdgcn_mfma_f32_16x16x32_f16(a, w0[0][ks], a0, 0, 0, 0);
                a1 = __builtin_amdgcn_mfma_f32_16x16x32_f16(a, w0[1][ks], a1, 0, 0, 0);
            }
            {
                f16x8 a = *(const f16x8*)(xbb + arow * 64 + ((lkg * 16) ^ xswz));
                a0 = __builtin_amdgcn_mfma_f32_16x16x32_f16(a, w0[0][8], a0, 0, 0, 0);
                a1 = __builtin_amdgcn_mfma_f32_16x16x32_f16(a, w0[1][8], a1, 0, 0, 0);
            }
#pragma unroll
            for (int r = 0; r < 4; ++r) {
                float v0 = a0[r] + b0[0], v1 = a1[r] + b0[1];
                float q0 = __shfl_xor(v0, 8);
                float q1 = __shfl_xor(v1, 8);
                float ig = lo ? v0 : q0, fg = lo ? q0 : v0;
                float gg = lo ? v1 : q1, og = lo ? q1 : v1;
                float c  = sigf(fg) * c0[mt][r] + sigf(ig) * tanh_f(gg);
                c0[mt][r] = c;
                float h  = sigf(og) * tanh_f(c);
                if (lo)
                    gx0w[(mt * 16 + lkg * 4 + r) * 32 + wv * 8 + lrow] =
                        __builtin_bit_cast(u16, (f16_t)h);
            }
        }
        __syncthreads();                 // drains vmcnt: all waves' gx0 stores visible
        if (tid == 0)
            __hip_atomic_fetch_add(c0p, 1u, __ATOMIC_RELEASE, __HIP_MEMORY_SCOPE_AGENT);

        // ---- GEMM1 h1-half (K from h1(t-1), already in LDS) — covers the c0 sync ----
        f32x4 accA[8] = {}, accB[8] = {};
#pragma unroll
        for (int mt = 0; mt < 8; ++mt) {
            const int arow = mt * 16 + lrow;
#pragma unroll
            for (int ks = 0; ks < 8; ++ks) {
                f16x8 a = *(const f16x8*)(h1b + arow * 512 + ((ks * 64 + lkg * 16) ^ aswz));
                accA[mt] = __builtin_amdgcn_mfma_f32_16x16x32_f16(a, w1[0][8 + ks], accA[mt], 0, 0, 0);
                accB[mt] = __builtin_amdgcn_mfma_f32_16x16x32_f16(a, w1[1][8 + ks], accB[mt], 0, 0, 0);
            }
        }

        // ---- h0 exchange: spin (mostly satisfied), fill full h0 tile; write x(t+1) ----
        if (tid == 0) {
            const unsigned tgt = 8u * (unsigned)(t + 1);
            while (__hip_atomic_load(c0p, __ATOMIC_ACQUIRE, __HIP_MEMORY_SCOPE_AGENT) < tgt)
                __builtin_amdgcn_s_sleep(1);
        }
        __syncthreads();
        {
            int row = tid >> 1, half = tid & 1;
            int sw = (row & 7) << 4;
#pragma unroll
            for (int s2 = 0; s2 < 8; ++s2) {
                const u16* src = gx0r + s2 * 4096 + row * 32 + half * 16;
                uint4 q0 = *(const uint4*)src;
                uint4 q1 = *(const uint4*)(src + 8);
                int cb = s2 * 64 + half * 32;
                *(uint4*)(h0b + row * 512 + (cb ^ sw)) = q0;
                *(uint4*)(h0b + row * 512 + ((cb + 16) ^ sw)) = q1;
            }
            if (t + 1 < T_STEPS) {
                int i0 = tid, i1 = tid + 256, i2 = tid + 512;
                { int row2 = i0 / 5, k = i0 - row2 * 5;
                  *(u16*)(xbb + row2 * 64 + ((2 * k) ^ ((row2 & 3) << 4))) = __builtin_bit_cast(u16, (f16_t)xv0); }
                { int row2 = i1 / 5, k = i1 - row2 * 5;
                  *(u16*)(xbb + row2 * 64 + ((2 * k) ^ ((row2 & 3) << 4))) = __builtin_bit_cast(u16, (f16_t)xv1); }
                if (i2 < GROWS * IN_DIM) {
                    int row2 = i2 / 5, k = i2 - row2 * 5;
                    *(u16*)(xbb + row2 * 64 + ((2 * k) ^ ((row2 & 3) << 4))) = __builtin_bit_cast(u16, (f16_t)xv2);
                }
            }
        }
        __syncthreads();

        // ---- GEMM1 h0-half + epilogue1: writes ONLY gx1 + c regs ----
#pragma unroll
        for (int mt = 0; mt < 8; ++mt) {
            const int arow = mt * 16 + lrow;
#pragma unroll
            for (int ks = 0; ks < 8; ++ks) {
                f16x8 a = *(const f16x8*)(h0b + arow * 512 + ((ks * 64 + lkg * 16) ^ aswz));
                accA[mt] = __builtin_amdgcn_mfma_f32_16x16x32_f16(a, w1[0][ks], accA[mt], 0, 0, 0);
                accB[mt] = __builtin_amdgcn_mfma_f32_16x16x32_f16(a, w1[1][ks], accB[mt], 0, 0, 0);
            }
#pragma unroll
            for (int r = 0; r < 4; ++r) {
                float v0 = accA[mt][r] + b1[0], v1 = accB[mt][r] + b1[1];
                float q0 = __shfl_xor(v0, 8);
                float q1 = __shfl_xor(v1, 8);
                float ig = lo ? v0 : q0, fg = lo ? q0 : v0;
                float gg = lo ? v1 : q1, og = lo ? q1 : v1;
                float c  = sigf(fg) * c1[mt][r] + sigf(ig) * tanh_f(gg);
                c1[mt][r] = c;
                float h  = sigf(og) * tanh_f(c);
                if (lo)
                    gx1w[(mt * 16 + lkg * 4 + r) * 32 + wv * 8 + lrow] =
                        __builtin_bit_cast(u16, (f16_t)h);
            }
        }
        __syncthreads();                 // gx1 stores visible
        if (tid == 0)
            __hip_atomic_fetch_add(c1p, 1u, __ATOMIC_RELEASE, __HIP_MEMORY_SCOPE_AGENT);

        // ---- deferred FC(t-1) from h1 LDS(t-1) (still intact) — covers the c1 sync ----
        if (t > 0) {
#pragma unroll 4
            for (int rr = 0; rr < 32; ++rr) {
                int row = wv * 32 + rr;
                uint2 raw = *(const uint2*)(h1b + row * 512 + ((lane * 8) ^ ((row & 7) << 4)));
                float s = (float)__builtin_bit_cast(f16_t, (u16)(raw.x & 0xffff)) * fcw[0]
                        + (float)__builtin_bit_cast(f16_t, (u16)(raw.x >> 16))    * fcw[1]
                        + (float)__builtin_bit_cast(f16_t, (u16)(raw.y & 0xffff)) * fcw[2]
                        + (float)__builtin_bit_cast(f16_t, (u16)(raw.y >> 16))    * fcw[3];
#pragma unroll
                for (int off = 32; off > 0; off >>= 1) s += __shfl_xor(s, off);
                if (lane == 0) out[(size_t)(r0 + row) * T_STEPS + (t - 1)] = s + fcb;
            }
        }

        // ---- h1 exchange: spin + fill full h1 tile ----
        if (tid == 0) {
            const unsigned tgt = 8u * (unsigned)(t + 1);
            while (__hip_atomic_load(c1p, __ATOMIC_ACQUIRE, __HIP_MEMORY_SCOPE_AGENT) < tgt)
                __builtin_amdgcn_s_sleep(1);
        }
        __syncthreads();
        {
            int row = tid >> 1, half = tid & 1;
            int sw = (row & 7) << 4;
#pragma unroll
            for (int s2 = 0; s2 < 8; ++s2) {
                const u16* src = gx1r + s2 * 4096 + row * 32 + half * 16;
                uint4 q0 = *(const uint4*)src;
                uint4 q1 = *(const uint4*)(src + 8);
                int cb = s2 * 64 + half * 32;
                *(uint4*)(h1b + row * 512 + (cb ^ sw)) = q0;
                *(uint4*)(h1b + row * 512 + ((cb + 16) ^ sw)) = q1;
            }
        }
        __syncthreads();
    }

    // ---- final FC for t = T-1 from h1(T-1) ----
#pragma unroll 4
    for (int rr = 0; rr < 32; ++rr) {
        int row = wv * 32 + rr;
        uint2 raw = *(const uint2*)(h1b + row * 512 + ((lane * 8) ^ ((row & 7) << 4)));
        float s = (float)__builtin_bit_cast(f16_t, (u16)(raw.x & 0xffff)) * fcw[0]
                + (float)__builtin_bit_cast(f16_t, (u16)(raw.x >> 16))    * fcw[1]
                + (float)__builtin_bit_cast(f16_t, (u16)(raw.y & 0xffff)) * fcw[2]
                + (float)__builtin_bit_cast(f16_t, (u16)(raw.y >> 16))    * fcw[3];
#pragma unroll
        for (int off = 32; off > 0; off >>= 1) s += __shfl_xor(s, off);
        if (lane == 0) out[(size_t)(r0 + row) * T_STEPS + (T_STEPS - 1)] = s + fcb;
    }
}

extern "C" void kernel_launch(void* const* d_in, const int* in_sizes, int n_in,
                              void* d_out, int out_size, void* d_ws, size_t ws_size,
                              hipStream_t stream)
{
    const float* x    = (const float*)d_in[0];
    const float* wih0 = (const float*)d_in[1];
    const float* whh0 = (const float*)d_in[2];
    const float* bih0 = (const float*)d_in[3];
    const float* bhh0 = (const float*)d_in[4];
    const float* wih1 = (const float*)d_in[5];
    const float* whh1 = (const float*)d_in[6];
    const float* bih1 = (const float*)d_in[7];
    const float* bhh1 = (const float*)d_in[8];
    const float* fcw  = (const float*)d_in[9];
    const float* fcb  = (const float*)d_in[10];

    u16* wsw      = (u16*)d_ws;
    float* biases = (float*)((char*)d_ws + WS_BIAS);
    u16* gxbase   = (u16*)((char*)d_ws + WS_GX);
    unsigned* cnt = (unsigned*)((char*)d_ws + WS_CNT);

    prep_kernel<<<416, 256, 0, stream>>>(wih0, whh0, wih1, whh1,
                                         bih0, bhh0, bih1, bhh1, wsw, biases, cnt);
    lstm_fused<<<NBLK, 256, 139264, stream>>>(x, wsw, biases, fcw, fcb,
                                              (float*)d_out, gxbase, cnt);
}

// Round 10
// 7806.904 us; speedup vs baseline: 1.4165x; 1.2661x over previous
//
#include <hip/hip_runtime.h>

typedef unsigned short u16;
typedef _Float16 f16_t;
typedef f16_t f16x8 __attribute__((ext_vector_type(8)));
typedef float f32x4 __attribute__((ext_vector_type(4)));

#define T_STEPS 256
#define IN_DIM  5
#define GROWS   128     // batch rows per 8-CU group
#define NBLK    256

// d_ws byte layout:
//   WS_W    @ 0       : weight frags [32 slice][50 frag][64 lane][16B] = 1,638,400
//   WS_BIAS @ 1638400 : f32 bias0[1024], bias1[1024]                    (8 KB)
//   WS_FC   @ 1646592 : fc_w B-frags [8 ks][64 lane][16B]               (8 KB)
//   WS_GX   @ 1654784 : u16 gx0[2 parity][32 grp][8 sub][128 row][32 col] (2 x 2 MB)
//                       u16 gx1[2 parity][...]                            (2 x 2 MB)
//   WS_CNT  @ 10043392: u32 cnt0[1024], cnt1[1024] (zeroed each launch by prep)
#define WS_BIAS 1638400
#define WS_FC   1646592
#define WS_GX   1654784
#define GXBUF   1048576                 // u16 elements per parity buffer (2 MB)
#define WS_CNT  (WS_GX + 4 * 2097152)

__device__ __forceinline__ float sigf(float x)  { return 1.0f / (1.0f + __expf(-x)); }
__device__ __forceinline__ float tanh_f(float x){ return 1.0f - 2.0f / (__expf(2.0f * x) + 1.0f); }

__global__ void prep_kernel(const float* __restrict__ wih0, const float* __restrict__ whh0,
                            const float* __restrict__ wih1, const float* __restrict__ whh1,
                            const float* __restrict__ bih0, const float* __restrict__ bhh0,
                            const float* __restrict__ bih1, const float* __restrict__ bhh1,
                            const float* __restrict__ fcw,
                            u16* __restrict__ wsw, float* __restrict__ biases,
                            u16* __restrict__ wsfc, unsigned* __restrict__ cnt)
{
    int j = blockIdx.x * blockDim.x + threadIdx.x;
    if (j < 102400) {
        // j = (slice*50 + f)*64 + lane ; slice = sub*4 + wv  (32 slices)
        int slice = j / 3200;
        int rem   = j - slice * 3200;
        int f     = rem >> 6;           // 0..49
        int lane  = rem & 63;
        int sub = slice >> 2, wv = slice & 3;
        int lrow = lane & 15;
        int kp = (lane >> 4) * 8;
        // gate-paired tiles: weight row = (nt*2 + hi)*256 + sub*32 + wv*8 + j
        int nt, ks; bool g0;
        if (f < 18) { g0 = true;  nt = f / 9;  ks = f - nt * 9; }
        else        { int ff = f - 18; g0 = false; nt = ff >> 4; ks = ff & 15; }
        int wr = (nt * 2 + (lrow >> 3)) * 256 + sub * 32 + wv * 8 + (lrow & 7);
        u16 tmp[8];
#pragma unroll
        for (int e = 0; e < 8; ++e) {
            int k = kp + e;
            float v;
            if (g0) {
                v = (ks < 8) ? whh0[wr * 256 + ks * 32 + k]
                             : (k < IN_DIM ? wih0[wr * IN_DIM + k] : 0.0f);
            } else {
                v = (ks < 8) ? wih1[wr * 256 + ks * 32 + k]
                             : whh1[wr * 256 + (ks - 8) * 32 + k];
            }
            tmp[e] = __builtin_bit_cast(u16, (f16_t)v);
        }
        *(uint4*)(wsw + (size_t)j * 8) = *(uint4*)tmp;
    } else if (j < 103424) {
        int i = j - 102400;
        biases[i] = bih0[i] + bhh0[i];
    } else if (j < 104448) {
        int i = j - 103424;
        biases[1024 + i] = bih1[i] + bhh1[i];
    } else if (j < 104960) {
        // fc_w as MFMA B-fragments: B[k][n] = (n==0) ? fcw[k] : 0
        int q = j - 104448;             // (ks*64 + lane)
        int ks = q >> 6, lane = q & 63;
        u16 tmp[8];
#pragma unroll
        for (int e = 0; e < 8; ++e) {
            float v = ((lane & 15) == 0) ? fcw[ks * 32 + (lane >> 4) * 8 + e] : 0.0f;
            tmp[e] = __builtin_bit_cast(u16, (f16_t)v);
        }
        *(uint4*)(wsfc + (size_t)q * 8) = *(uint4*)tmp;
    } else if (j < 107008) {
        cnt[j - 104960] = 0u;
    }
}

__global__ __launch_bounds__(256, 1) void lstm_fused(
    const float* __restrict__ x, const u16* __restrict__ wsw,
    const float* __restrict__ biases, const u16* __restrict__ wsfc,
    const float* __restrict__ fcb_g, float* __restrict__ out,
    u16* __restrict__ gxbase, unsigned* __restrict__ cnt)
{
    extern __shared__ char smem[];
    char* h0b = smem;                  // [128 rows][512B] fp16, XOR-swizzled
    char* h1b = smem + 65536;          // [128 rows][512B]
    char* xbb = smem + 131072;         // [128 rows][64B] x_t staged (zero-padded)

    const int tid  = threadIdx.x;
    const int wv   = tid >> 6;         // wave 0..3: hidden cols sub*32 + wv*8 .. +8, all 4 gates
    const int lane = tid & 63;
    const int lrow = lane & 15;
    const int lkg  = lane >> 4;
    const int hf   = lrow >> 3;        // gate-half: 0 -> (i,g) tiles, 1 -> (f,o)
    const int cj   = lrow & 7;         // column within wave slice
    const int sub  = blockIdx.x >> 5;  // CU index within group (0..7)
    const int grp  = blockIdx.x & 31;  // group; members {g, g+32, ..., g+224}
    const int r0   = grp * GROWS;
    const int aswz = (lrow & 7) << 4;
    const int xswz = (lrow & 3) << 4;

    // ---- resident weights: 50 shard frags + 8 FC frags = 232 AGPRs/lane ----
    f16x8 w0[2][9], w1[2][16], wfc[8];
    const u16* wbase = wsw + (size_t)(sub * 4 + wv) * 25600;
#pragma unroll
    for (int nt = 0; nt < 2; ++nt)
#pragma unroll
        for (int ks = 0; ks < 9; ++ks) {
            w0[nt][ks] = *(const f16x8*)(wbase + (nt * 9 + ks) * 512 + lane * 8);
            asm volatile("" : "+a"(w0[nt][ks]));
            __builtin_amdgcn_sched_barrier(0);
        }
#pragma unroll
    for (int nt = 0; nt < 2; ++nt)
#pragma unroll
        for (int ks = 0; ks < 16; ++ks) {
            w1[nt][ks] = *(const f16x8*)(wbase + (18 + nt * 16 + ks) * 512 + lane * 8);
            asm volatile("" : "+a"(w1[nt][ks]));
            __builtin_amdgcn_sched_barrier(0);
        }
#pragma unroll
    for (int ks = 0; ks < 8; ++ks) {
        wfc[ks] = *(const f16x8*)(wsfc + ks * 512 + lane * 8);
        asm volatile("" : "+a"(wfc[ks]));
        __builtin_amdgcn_sched_barrier(0);
    }

    float b0[2], b1[2];
#pragma unroll
    for (int nt = 0; nt < 2; ++nt) {
        int wr = (nt * 2 + hf) * 256 + sub * 32 + wv * 8 + cj;
        b0[nt] = biases[wr];
        b1[nt] = biases[1024 + wr];
    }
    const float fcb = fcb_g[0];

    unsigned* c0p = cnt + grp * 16;
    unsigned* c1p = cnt + 1024 + grp * 16;

    // zero LDS (h0, h1, xbb incl pads)
    for (int i = tid; i < 139264 / 4; i += 256) ((unsigned*)smem)[i] = 0u;
    __syncthreads();
    // stage x_0
    for (int i = tid; i < GROWS * IN_DIM; i += 256) {
        int row = i / 5, k = i - row * 5;
        float v = x[((size_t)(r0 + row) * T_STEPS + 0) * IN_DIM + k];
        *(u16*)(xbb + row * 64 + ((2 * k) ^ ((row & 3) << 4))) = __builtin_bit_cast(u16, (f16_t)v);
    }
    __syncthreads();

    float c0[8][2] = {};   // c-state: lane holds rows (mt*16+lkg*4+hf*2+rr), col cj
    float c1[8][2] = {};

#pragma unroll 1
    for (int t = 0; t < T_STEPS; ++t) {
        const int p = t & 1;
        u16* gx0w = gxbase + (size_t)p * GXBUF + (size_t)(grp * 8 + sub) * 4096;
        u16* gx1w = gxbase + (size_t)(2 + p) * GXBUF + (size_t)(grp * 8 + sub) * 4096;
        const u16* gx0r = gxbase + (size_t)p * GXBUF + (size_t)grp * 8 * 4096;
        const u16* gx1r = gxbase + (size_t)(2 + (p ^ 1)) * GXBUF + (size_t)grp * 8 * 4096;

        // issue x(t+1) loads early; latency hides under GEMM0
        float xv0 = 0.f, xv1 = 0.f, xv2 = 0.f;
        if (t + 1 < T_STEPS) {
            int i0 = tid, i1 = tid + 256, i2 = tid + 512;
            { int row = i0 / 5, k = i0 - row * 5;
              xv0 = x[((size_t)(r0 + row) * T_STEPS + (t + 1)) * IN_DIM + k]; }
            { int row = i1 / 5, k = i1 - row * 5;
              xv1 = x[((size_t)(r0 + row) * T_STEPS + (t + 1)) * IN_DIM + k]; }
            if (i2 < GROWS * IN_DIM) {
                int row = i2 / 5, k = i2 - row * 5;
                xv2 = x[((size_t)(r0 + row) * T_STEPS + (t + 1)) * IN_DIM + k];
            }
        }

        // ---- A: GEMM0 + de-dup epilogue0 -> publish gx0 ----
#pragma unroll
        for (int mt = 0; mt < 8; ++mt) {
            f32x4 a0 = {}, a1 = {};
            const int arow = mt * 16 + lrow;
#pragma unroll
            for (int ks = 0; ks < 8; ++ks) {
                f16x8 a = *(const f16x8*)(h0b + arow * 512 + ((ks * 64 + lkg * 16) ^ aswz));
                a0 = __builtin_amdgcn_mfma_f32_16x16x32_f16(a, w0[0][ks], a0, 0, 0, 0);
                a1 = __builtin_amdgcn_mfma_f32_16x16x32_f16(a, w0[1][ks], a1, 0, 0, 0);
            }
            {
                f16x8 a = *(const f16x8*)(xbb + arow * 64 + ((lkg * 16) ^ xswz));
                a0 = __builtin_amdgcn_mfma_f32_16x16x32_f16(a, w0[0][8], a0, 0, 0, 0);
                a1 = __builtin_amdgcn_mfma_f32_16x16x32_f16(a, w0[1][8], a1, 0, 0, 0);
            }
            // biases first so shuffled values carry them
#pragma unroll
            for (int r = 0; r < 4; ++r) { a0[r] += b0[0]; a1[r] += b0[1]; }
            // redistribute gates: lo lanes own r={0,1}, hi lanes r={2,3}
            float sA0 = __shfl_xor(hf ? a0[0] : a0[2], 8);
            float sA1 = __shfl_xor(hf ? a0[1] : a0[3], 8);
            float sB0 = __shfl_xor(hf ? a1[0] : a1[2], 8);
            float sB1 = __shfl_xor(hf ? a1[1] : a1[3], 8);
#pragma unroll
            for (int rr = 0; rr < 2; ++rr) {
                float sa = rr ? sA1 : sA0, sb = rr ? sB1 : sB0;
                float ig = hf ? sa : a0[rr];
                float fg = hf ? a0[2 + rr] : sa;
                float gg = hf ? sb : a1[rr];
                float og = hf ? a1[2 + rr] : sb;
                float c  = sigf(fg) * c0[mt][rr] + sigf(ig) * tanh_f(gg);
                c0[mt][rr] = c;
                float h  = sigf(og) * tanh_f(c);
                int row = mt * 16 + lkg * 4 + hf * 2 + rr;
                gx0w[row * 32 + wv * 8 + cj] = __builtin_bit_cast(u16, (f16_t)h);
            }
        }
        __syncthreads();                 // drains vmcnt: gx0 stores retired
        if (tid == 0)
            __hip_atomic_fetch_add(c0p, 1u, __ATOMIC_RELEASE, __HIP_MEMORY_SCOPE_AGENT);

        // ---- S1: single merged spin (c0(t) AND c1(t-1)), then both fills ----
        if (tid == 0) {
            unsigned tgt = 8u * (unsigned)(t + 1);
            while (__hip_atomic_load(c0p, __ATOMIC_ACQUIRE, __HIP_MEMORY_SCOPE_AGENT) < tgt)
                __builtin_amdgcn_s_sleep(1);
            if (t > 0) {
                unsigned tgt1 = 8u * (unsigned)t;
                while (__hip_atomic_load(c1p, __ATOMIC_ACQUIRE, __HIP_MEMORY_SCOPE_AGENT) < tgt1)
                    __builtin_amdgcn_s_sleep(1);
            }
        }
        __syncthreads();
        {
            int row = tid >> 1, half = tid & 1;
            int sw = (row & 7) << 4;
#pragma unroll
            for (int s2 = 0; s2 < 8; ++s2) {
                const u16* src = gx0r + s2 * 4096 + row * 32 + half * 16;
                uint4 q0 = *(const uint4*)src;
                uint4 q1 = *(const uint4*)(src + 8);
                int cb = s2 * 64 + half * 32;
                *(uint4*)(h0b + row * 512 + (cb ^ sw)) = q0;
                *(uint4*)(h0b + row * 512 + ((cb + 16) ^ sw)) = q1;
            }
            if (t > 0) {
#pragma unroll
                for (int s2 = 0; s2 < 8; ++s2) {
                    const u16* src = gx1r + s2 * 4096 + row * 32 + half * 16;
                    uint4 q0 = *(const uint4*)src;
                    uint4 q1 = *(const uint4*)(src + 8);
                    int cb = s2 * 64 + half * 32;
                    *(uint4*)(h1b + row * 512 + (cb ^ sw)) = q0;
                    *(uint4*)(h1b + row * 512 + ((cb + 16) ^ sw)) = q1;
                }
            }
            if (t + 1 < T_STEPS) {
                int i0 = tid, i1 = tid + 256, i2 = tid + 512;
                { int row2 = i0 / 5, k = i0 - row2 * 5;
                  *(u16*)(xbb + row2 * 64 + ((2 * k) ^ ((row2 & 3) << 4))) = __builtin_bit_cast(u16, (f16_t)xv0); }
                { int row2 = i1 / 5, k = i1 - row2 * 5;
                  *(u16*)(xbb + row2 * 64 + ((2 * k) ^ ((row2 & 3) << 4))) = __builtin_bit_cast(u16, (f16_t)xv1); }
                if (i2 < GROWS * IN_DIM) {
                    int row2 = i2 / 5, k = i2 - row2 * 5;
                    *(u16*)(xbb + row2 * 64 + ((2 * k) ^ ((row2 & 3) << 4))) = __builtin_bit_cast(u16, (f16_t)xv2);
                }
            }
        }
        __syncthreads();

        // ---- F: FC(t-1) via MFMA on h1(t-1); CU 'sub' emits its 16 rows ----
        if (t > 0 && wv == 0) {
            f32x4 acc = {};
            const int arow = sub * 16 + lrow;
#pragma unroll
            for (int ks = 0; ks < 8; ++ks) {
                f16x8 a = *(const f16x8*)(h1b + arow * 512 + ((ks * 64 + lkg * 16) ^ aswz));
                acc = __builtin_amdgcn_mfma_f32_16x16x32_f16(a, wfc[ks], acc, 0, 0, 0);
            }
            if (lrow == 0) {
#pragma unroll
                for (int r = 0; r < 4; ++r)
                    out[(size_t)(r0 + sub * 16 + lkg * 4 + r) * T_STEPS + (t - 1)] = acc[r] + fcb;
            }
        }

        // ---- B: GEMM1 (full K: h0(t) then h1(t-1)) + de-dup epilogue1 ----
#pragma unroll
        for (int mt = 0; mt < 8; ++mt) {
            f32x4 a0 = {}, a1 = {};
            const int arow = mt * 16 + lrow;
#pragma unroll
            for (int ks = 0; ks < 8; ++ks) {
                f16x8 a = *(const f16x8*)(h0b + arow * 512 + ((ks * 64 + lkg * 16) ^ aswz));
                a0 = __builtin_amdgcn_mfma_f32_16x16x32_f16(a, w1[0][ks], a0, 0, 0, 0);
                a1 = __builtin_amdgcn_mfma_f32_16x16x32_f16(a, w1[1][ks], a1, 0, 0, 0);
            }
#pragma unroll
            for (int ks = 0; ks < 8; ++ks) {
                f16x8 a = *(const f16x8*)(h1b + arow * 512 + ((ks * 64 + lkg * 16) ^ aswz));
                a0 = __builtin_amdgcn_mfma_f32_16x16x32_f16(a, w1[0][8 + ks], a0, 0, 0, 0);
                a1 = __builtin_amdgcn_mfma_f32_16x16x32_f16(a, w1[1][8 + ks], a1, 0, 0, 0);
            }
#pragma unroll
            for (int r = 0; r < 4; ++r) { a0[r] += b1[0]; a1[r] += b1[1]; }
            float sA0 = __shfl_xor(hf ? a0[0] : a0[2], 8);
            float sA1 = __shfl_xor(hf ? a0[1] : a0[3], 8);
            float sB0 = __shfl_xor(hf ? a1[0] : a1[2], 8);
            float sB1 = __shfl_xor(hf ? a1[1] : a1[3], 8);
#pragma unroll
            for (int rr = 0; rr < 2; ++rr) {
                float sa = rr ? sA1 : sA0, sb = rr ? sB1 : sB0;
                float ig = hf ? sa : a0[rr];
                float fg = hf ? a0[2 + rr] : sa;
                float gg = hf ? sb : a1[rr];
                float og = hf ? a1[2 + rr] : sb;
                float c  = sigf(fg) * c1[mt][rr] + sigf(ig) * tanh_f(gg);
                c1[mt][rr] = c;
                float h  = sigf(og) * tanh_f(c);
                int row = mt * 16 + lkg * 4 + hf * 2 + rr;
                gx1w[row * 32 + wv * 8 + cj] = __builtin_bit_cast(u16, (f16_t)h);
            }
        }
        __syncthreads();                 // gx1 stores retired
        if (tid == 0)
            __hip_atomic_fetch_add(c1p, 1u, __ATOMIC_RELEASE, __HIP_MEMORY_SCOPE_AGENT);
    }

    // ---- loop epilogue: fill h1(T-1), emit FC(T-1) ----
    if (tid == 0) {
        unsigned tgt = 8u * (unsigned)T_STEPS;
        while (__hip_atomic_load(c1p, __ATOMIC_ACQUIRE, __HIP_MEMORY_SCOPE_AGENT) < tgt)
            __builtin_amdgcn_s_sleep(1);
    }
    __syncthreads();
    {
        const u16* gx1r = gxbase + (size_t)(2 + ((T_STEPS - 1) & 1)) * GXBUF + (size_t)grp * 8 * 4096;
        int row = tid >> 1, half = tid & 1;
        int sw = (row & 7) << 4;
#pragma unroll
        for (int s2 = 0; s2 < 8; ++s2) {
            const u16* src = gx1r + s2 * 4096 + row * 32 + half * 16;
            uint4 q0 = *(const uint4*)src;
            uint4 q1 = *(const uint4*)(src + 8);
            int cb = s2 * 64 + half * 32;
            *(uint4*)(h1b + row * 512 + (cb ^ sw)) = q0;
            *(uint4*)(h1b + row * 512 + ((cb + 16) ^ sw)) = q1;
        }
    }
    __syncthreads();
    if (wv == 0) {
        f32x4 acc = {};
        const int arow = sub * 16 + lrow;
#pragma unroll
        for (int ks = 0; ks < 8; ++ks) {
            f16x8 a = *(const f16x8*)(h1b + arow * 512 + ((ks * 64 + lkg * 16) ^ aswz));
            acc = __builtin_amdgcn_mfma_f32_16x16x32_f16(a, wfc[ks], acc, 0, 0, 0);
        }
        if (lrow == 0) {
#pragma unroll
            for (int r = 0; r < 4; ++r)
                out[(size_t)(r0 + sub * 16 + lkg * 4 + r) * T_STEPS + (T_STEPS - 1)] = acc[r] + fcb;
        }
    }
}

extern "C" void kernel_launch(void* const* d_in, const int* in_sizes, int n_in,
                              void* d_out, int out_size, void* d_ws, size_t ws_size,
                              hipStream_t stream)
{
    const float* x    = (const float*)d_in[0];
    const float* wih0 = (const float*)d_in[1];
    const float* whh0 = (const float*)d_in[2];
    const float* bih0 = (const float*)d_in[3];
    const float* bhh0 = (const float*)d_in[4];
    const float* wih1 = (const float*)d_in[5];
    const float* whh1 = (const float*)d_in[6];
    const float* bih1 = (const float*)d_in[7];
    const float* bhh1 = (const float*)d_in[8];
    const float* fcw  = (const float*)d_in[9];
    const float* fcb  = (const float*)d_in[10];

    u16* wsw      = (u16*)d_ws;
    float* biases = (float*)((char*)d_ws + WS_BIAS);
    u16* wsfc     = (u16*)((char*)d_ws + WS_FC);
    u16* gxbase   = (u16*)((char*)d_ws + WS_GX);
    unsigned* cnt = (unsigned*)((char*)d_ws + WS_CNT);

    prep_kernel<<<419, 256, 0, stream>>>(wih0, whh0, wih1, whh1,
                                         bih0, bhh0, bih1, bhh1, fcw,
                                         wsw, biases, wsfc, cnt);
    lstm_fused<<<NBLK, 256, 139264, stream>>>(x, wsw, biases, wsfc, fcb,
                                              (float*)d_out, gxbase, cnt);
}

// Round 13
// 7213.940 us; speedup vs baseline: 1.5330x; 1.0822x over previous
//
#include <hip/hip_runtime.h>

typedef unsigned short u16;
typedef _Float16 f16_t;
typedef f16_t f16x8 __attribute__((ext_vector_type(8)));
typedef float f32x4 __attribute__((ext_vector_type(4)));

#define T_STEPS 256
#define IN_DIM  5
#define NBLK    256

// d_ws byte layout:
//   WS_W    @ 0       : weight frags [32 slice][50 frag][64 lane][16B] = 1,638,400
//   WS_BIAS @ 1638400 : f32 bias0[1024], bias1[1024]                    (8 KB)
//   WS_FC   @ 1646592 : fc_w B-frags [8 ks][64 lane][16B]               (8 KB)
//   WS_GX   @ 1654784 : u16 gx[(stream*2+which)*2+parity][32 grp][8 sub][64 row][32 col]
//                       8 buffers x 1 MB = 8 MB
//   WS_CNT  @ 10043392: u32 cntA[1024], cntB[1024] (zeroed each launch by prep)
#define WS_BIAS 1638400
#define WS_FC   1646592
#define WS_GX   1654784
#define GXS     524288                  // u16 elements per (stream,which,parity) buffer
#define WS_CNT  (WS_GX + 8388608)

__device__ __forceinline__ float sigf(float x)  { return 1.0f / (1.0f + __expf(-x)); }
__device__ __forceinline__ float tanh_f(float x){ return 1.0f - 2.0f / (__expf(2.0f * x) + 1.0f); }

__global__ void prep_kernel(const float* __restrict__ wih0, const float* __restrict__ whh0,
                            const float* __restrict__ wih1, const float* __restrict__ whh1,
                            const float* __restrict__ bih0, const float* __restrict__ bhh0,
                            const float* __restrict__ bih1, const float* __restrict__ bhh1,
                            const float* __restrict__ fcw,
                            u16* __restrict__ wsw, float* __restrict__ biases,
                            u16* __restrict__ wsfc, unsigned* __restrict__ cnt)
{
    int j = blockIdx.x * blockDim.x + threadIdx.x;
    if (j < 102400) {
        // j = (slice*50 + f)*64 + lane ; slice = sub*4 + wv  (32 slices)
        int slice = j / 3200;
        int rem   = j - slice * 3200;
        int f     = rem >> 6;           // 0..49
        int lane  = rem & 63;
        int sub = slice >> 2, wv = slice & 3;
        int lrow = lane & 15;
        int kp = (lane >> 4) * 8;
        int nt, ks; bool g0;
        if (f < 18) { g0 = true;  nt = f / 9;  ks = f - nt * 9; }
        else        { int ff = f - 18; g0 = false; nt = ff >> 4; ks = ff & 15; }
        int wr = (nt * 2 + (lrow >> 3)) * 256 + sub * 32 + wv * 8 + (lrow & 7);
        u16 tmp[8];
#pragma unroll
        for (int e = 0; e < 8; ++e) {
            int k = kp + e;
            float v;
            if (g0) {
                v = (ks < 8) ? whh0[wr * 256 + ks * 32 + k]
                             : (k < IN_DIM ? wih0[wr * IN_DIM + k] : 0.0f);
            } else {
                v = (ks < 8) ? wih1[wr * 256 + ks * 32 + k]
                             : whh1[wr * 256 + (ks - 8) * 32 + k];
            }
            tmp[e] = __builtin_bit_cast(u16, (f16_t)v);
        }
        *(uint4*)(wsw + (size_t)j * 8) = *(uint4*)tmp;
    } else if (j < 103424) {
        int i = j - 102400;
        biases[i] = bih0[i] + bhh0[i];
    } else if (j < 104448) {
        int i = j - 103424;
        biases[1024 + i] = bih1[i] + bhh1[i];
    } else if (j < 104960) {
        // fc_w as MFMA B-fragments: B[k][n] = (n==0) ? fcw[k] : 0
        int q = j - 104448;
        int ks = q >> 6, lane = q & 63;
        u16 tmp[8];
#pragma unroll
        for (int e = 0; e < 8; ++e) {
            float v = ((lane & 15) == 0) ? fcw[ks * 32 + (lane >> 4) * 8 + e] : 0.0f;
            tmp[e] = __builtin_bit_cast(u16, (f16_t)v);
        }
        *(uint4*)(wsfc + (size_t)q * 8) = *(uint4*)tmp;
    } else if (j < 107008) {
        cnt[j - 104960] = 0u;
    }
}

__global__ __launch_bounds__(256, 1) void lstm_fused(
    const float* __restrict__ x, const u16* __restrict__ wsw,
    const float* __restrict__ biases, const u16* __restrict__ wsfc,
    const float* __restrict__ fcb_g, float* __restrict__ out,
    u16* __restrict__ gxbase, unsigned* __restrict__ cnt)
{
    extern __shared__ char smem[];
    char* h0A = smem;                  // [64 rows][512B] fp16, XOR-swizzled
    char* h1A = smem + 32768;
    char* xbA = smem + 65536;          // [64 rows][64B]
    char* h0B = smem + 69632;
    char* h1B = smem + 102400;
    char* xbB = smem + 135168;         // ends at 139264

    const int tid  = threadIdx.x;
    const int wv   = tid >> 6;
    const int lane = tid & 63;
    const int lrow = lane & 15;
    const int lkg  = lane >> 4;
    const int hf   = lrow >> 3;        // gate-half: 0 -> (i,g), 1 -> (f,o)
    const int cj   = lrow & 7;
    const int sub  = blockIdx.x >> 5;  // CU in group (0..7)
    const int grp  = blockIdx.x & 31;  // members {g, g+32, ...}
    const int r0   = grp * 128;        // group owns 128 batch rows; A: +0..63, B: +64..127
    const int aswz = (lrow & 7) << 4;
    const int xswz = (lrow & 3) << 4;

    // ---- resident weights: 50 shard frags + 8 FC frags = 232 AGPRs/lane ----
    f16x8 w0[2][9], w1[2][16], wfc[8];
    const u16* wbase = wsw + (size_t)(sub * 4 + wv) * 25600;
#pragma unroll
    for (int nt = 0; nt < 2; ++nt)
#pragma unroll
        for (int ks = 0; ks < 9; ++ks) {
            w0[nt][ks] = *(const f16x8*)(wbase + (nt * 9 + ks) * 512 + lane * 8);
            asm volatile("" : "+a"(w0[nt][ks]));
            __builtin_amdgcn_sched_barrier(0);
        }
#pragma unroll
    for (int nt = 0; nt < 2; ++nt)
#pragma unroll
        for (int ks = 0; ks < 16; ++ks) {
            w1[nt][ks] = *(const f16x8*)(wbase + (18 + nt * 16 + ks) * 512 + lane * 8);
            asm volatile("" : "+a"(w1[nt][ks]));
            __builtin_amdgcn_sched_barrier(0);
        }
#pragma unroll
    for (int ks = 0; ks < 8; ++ks) {
        wfc[ks] = *(const f16x8*)(wsfc + ks * 512 + lane * 8);
        asm volatile("" : "+a"(wfc[ks]));
        __builtin_amdgcn_sched_barrier(0);
    }

    float b0[2], b1[2];
#pragma unroll
    for (int nt = 0; nt < 2; ++nt) {
        int wr = (nt * 2 + hf) * 256 + sub * 32 + wv * 8 + cj;
        b0[nt] = biases[wr];
        b1[nt] = biases[1024 + wr];
    }
    const float fcb = fcb_g[0];

    unsigned* cA = cnt + grp * 16;
    unsigned* cB = cnt + 1024 + grp * 16;

    auto gxr = [&](int stream, int which, int parity) -> u16* {
        return gxbase + (size_t)((stream * 2 + which) * 2 + parity) * GXS + grp * 16384;
    };

    // zero all LDS
    for (int i = tid; i < 139264 / 4; i += 256) ((unsigned*)smem)[i] = 0u;
    __syncthreads();
    // stage xA(0)
    {
        int i0 = tid, i1 = tid + 256;
        if (i0 < 320) { int row = i0 / 5, k = i0 - row * 5;
            float v = x[((size_t)(r0 + row) * T_STEPS + 0) * IN_DIM + k];
            *(u16*)(xbA + row * 64 + ((2 * k) ^ ((row & 3) << 4))) = __builtin_bit_cast(u16, (f16_t)v); }
        if (i1 < 320) { int row = i1 / 5, k = i1 - row * 5;
            float v = x[((size_t)(r0 + row) * T_STEPS + 0) * IN_DIM + k];
            *(u16*)(xbA + row * 64 + ((2 * k) ^ ((row & 3) << 4))) = __builtin_bit_cast(u16, (f16_t)v); }
    }
    __syncthreads();

    float c0A[4][2] = {}, c1A[4][2] = {}, c0B[4][2] = {}, c1B[4][2] = {};

    // ---- phase helpers ----
    auto GEMM0 = [&](const char* h0s, const char* xbs, float (&cs)[4][2], u16* gxw) {
#pragma unroll
        for (int mt = 0; mt < 4; ++mt) {
            f32x4 a0 = {}, a1 = {};
            const int arow = mt * 16 + lrow;
#pragma unroll
            for (int ks = 0; ks < 8; ++ks) {
                f16x8 a = *(const f16x8*)(h0s + arow * 512 + ((ks * 64 + lkg * 16) ^ aswz));
                a0 = __builtin_amdgcn_mfma_f32_16x16x32_f16(a, w0[0][ks], a0, 0, 0, 0);
                a1 = __builtin_amdgcn_mfma_f32_16x16x32_f16(a, w0[1][ks], a1, 0, 0, 0);
            }
            {
                f16x8 a = *(const f16x8*)(xbs + arow * 64 + ((lkg * 16) ^ xswz));
                a0 = __builtin_amdgcn_mfma_f32_16x16x32_f16(a, w0[0][8], a0, 0, 0, 0);
                a1 = __builtin_amdgcn_mfma_f32_16x16x32_f16(a, w0[1][8], a1, 0, 0, 0);
            }
#pragma unroll
            for (int r = 0; r < 4; ++r) { a0[r] += b0[0]; a1[r] += b0[1]; }
            float sA0 = __shfl_xor(hf ? a0[0] : a0[2], 8);
            float sA1 = __shfl_xor(hf ? a0[1] : a0[3], 8);
            float sB0 = __shfl_xor(hf ? a1[0] : a1[2], 8);
            float sB1 = __shfl_xor(hf ? a1[1] : a1[3], 8);
#pragma unroll
            for (int rr = 0; rr < 2; ++rr) {
                float sa = rr ? sA1 : sA0, sb = rr ? sB1 : sB0;
                float ig = hf ? sa : a0[rr];
                float fg = hf ? a0[2 + rr] : sa;
                float gg = hf ? sb : a1[rr];
                float og = hf ? a1[2 + rr] : sb;
                float c  = sigf(fg) * cs[mt][rr] + sigf(ig) * tanh_f(gg);
                cs[mt][rr] = c;
                float h  = sigf(og) * tanh_f(c);
                int row = mt * 16 + lkg * 4 + hf * 2 + rr;
                gxw[sub * 2048 + row * 32 + wv * 8 + cj] = __builtin_bit_cast(u16, (f16_t)h);
            }
        }
    };
    auto GEMM1 = [&](const char* h0s, const char* h1s, float (&cs)[4][2], u16* gxw) {
#pragma unroll
        for (int mt = 0; mt < 4; ++mt) {
            f32x4 a0 = {}, a1 = {};
            const int arow = mt * 16 + lrow;
#pragma unroll
            for (int ks = 0; ks < 8; ++ks) {
                f16x8 a = *(const f16x8*)(h0s + arow * 512 + ((ks * 64 + lkg * 16) ^ aswz));
                a0 = __builtin_amdgcn_mfma_f32_16x16x32_f16(a, w1[0][ks], a0, 0, 0, 0);
                a1 = __builtin_amdgcn_mfma_f32_16x16x32_f16(a, w1[1][ks], a1, 0, 0, 0);
            }
#pragma unroll
            for (int ks = 0; ks < 8; ++ks) {
                f16x8 a = *(const f16x8*)(h1s + arow * 512 + ((ks * 64 + lkg * 16) ^ aswz));
                a0 = __builtin_amdgcn_mfma_f32_16x16x32_f16(a, w1[0][8 + ks], a0, 0, 0, 0);
                a1 = __builtin_amdgcn_mfma_f32_16x16x32_f16(a, w1[1][8 + ks], a1, 0, 0, 0);
            }
#pragma unroll
            for (int r = 0; r < 4; ++r) { a0[r] += b1[0]; a1[r] += b1[1]; }
            float sA0 = __shfl_xor(hf ? a0[0] : a0[2], 8);
            float sA1 = __shfl_xor(hf ? a0[1] : a0[3], 8);
            float sB0 = __shfl_xor(hf ? a1[0] : a1[2], 8);
            float sB1 = __shfl_xor(hf ? a1[1] : a1[3], 8);
#pragma unroll
            for (int rr = 0; rr < 2; ++rr) {
                float sa = rr ? sA1 : sA0, sb = rr ? sB1 : sB0;
                float ig = hf ? sa : a0[rr];
                float fg = hf ? a0[2 + rr] : sa;
                float gg = hf ? sb : a1[rr];
                float og = hf ? a1[2 + rr] : sb;
                float c  = sigf(fg) * cs[mt][rr] + sigf(ig) * tanh_f(gg);
                cs[mt][rr] = c;
                float h  = sigf(og) * tanh_f(c);
                int row = mt * 16 + lkg * 4 + hf * 2 + rr;
                gxw[sub * 2048 + row * 32 + wv * 8 + cj] = __builtin_bit_cast(u16, (f16_t)h);
            }
        }
    };
    auto RELEASE = [&](unsigned* p) {
        __syncthreads();               // drains vmcnt: gx stores retired before release
        if (tid == 0)
            __hip_atomic_fetch_add(p, 1u, __ATOMIC_RELEASE, __HIP_MEMORY_SCOPE_AGENT);
    };
    auto SPIN = [&](unsigned* p, unsigned tgt) {
        if (tid == 0) {
            while (__hip_atomic_load(p, __ATOMIC_RELAXED, __HIP_MEMORY_SCOPE_AGENT) < tgt)
                __builtin_amdgcn_s_sleep(1);
            (void)__hip_atomic_load(p, __ATOMIC_ACQUIRE, __HIP_MEMORY_SCOPE_AGENT);
        }
        __syncthreads();
    };
    auto FILL = [&](char* dst, const u16* src) {
        int row = tid & 63, q = tid >> 6;
        int sw = (row & 7) << 4;
#pragma unroll
        for (int ss = 0; ss < 2; ++ss) {
            int s2 = q * 2 + ss;
            const u16* sp = src + s2 * 2048 + row * 32;
#pragma unroll
            for (int j = 0; j < 4; ++j) {
                uint4 v = *(const uint4*)(sp + j * 8);
                *(uint4*)(dst + row * 512 + ((s2 * 64 + j * 16) ^ sw)) = v;
            }
        }
    };
    auto XLOAD = [&](int strOff, int tt, float& v0, float& v1) {
        v0 = 0.f; v1 = 0.f;
        int i0 = tid, i1 = tid + 256;
        if (i0 < 320) { int row = i0 / 5, k = i0 - row * 5;
            v0 = x[((size_t)(r0 + strOff + row) * T_STEPS + tt) * IN_DIM + k]; }
        if (i1 < 320) { int row = i1 / 5, k = i1 - row * 5;
            v1 = x[((size_t)(r0 + strOff + row) * T_STEPS + tt) * IN_DIM + k]; }
    };
    auto XSTAGE = [&](char* xbs, float v0, float v1) {
        int i0 = tid, i1 = tid + 256;
        if (i0 < 320) { int row = i0 / 5, k = i0 - row * 5;
            *(u16*)(xbs + row * 64 + ((2 * k) ^ ((row & 3) << 4))) = __builtin_bit_cast(u16, (f16_t)v0); }
        if (i1 < 320) { int row = i1 / 5, k = i1 - row * 5;
            *(u16*)(xbs + row * 64 + ((2 * k) ^ ((row & 3) << 4))) = __builtin_bit_cast(u16, (f16_t)v1); }
    };
    auto FC = [&](const char* h1s, int strOff, int tIdx, bool mine, int sub4) {
        if (wv == 0 && mine) {
            f32x4 acc = {};
            const int arow = sub4 * 16 + lrow;
#pragma unroll
            for (int ks = 0; ks < 8; ++ks) {
                f16x8 a = *(const f16x8*)(h1s + arow * 512 + ((ks * 64 + lkg * 16) ^ aswz));
                acc = __builtin_amdgcn_mfma_f32_16x16x32_f16(a, wfc[ks], acc, 0, 0, 0);
            }
            if (lrow == 0) {
#pragma unroll
                for (int r = 0; r < 4; ++r)
                    out[(size_t)(r0 + strOff + sub4 * 16 + lkg * 4 + r) * T_STEPS + tIdx] = acc[r] + fcb;
            }
        }
    };

#pragma unroll 1
    for (int t = 0; t < T_STEPS; ++t) {
        const int pc = t & 1, pp = (t - 1) & 1;   // current / previous parity

        // x prefetch: xA(t+1) staged in S_A, xB(t) staged in S_B
        float xa0, xa1, xbv0, xbv1;
        if (t + 1 < T_STEPS) { XLOAD(0, t + 1, xa0, xa1); } else { xa0 = 0.f; xa1 = 0.f; }
        XLOAD(64, t, xbv0, xbv1);

        // ---- C_A: GEMM0_A(t) + GEMM1_A(t-1), publish, release ----
        GEMM0(h0A, xbA, c0A, gxr(0, 0, pc));
        if (t > 0) GEMM1(h0A, h1A, c1A, gxr(0, 1, pp));
        RELEASE(cA);

        // ---- S_B: spin for B's releases of iter t-1 (covered by C_A) ----
        SPIN(cB, 8u * (unsigned)t);               // t=0: trivially passes
        if (t > 0) FILL(h0B, gxr(1, 0, pp));      // h0B(t-1)
        if (t > 1) FILL(h1B, gxr(1, 1, pc));      // h1B(t-2): parity (t-2)&1 == t&1
        XSTAGE(xbB, xbv0, xbv1);                  // xB(t)
        __syncthreads();
        if (t > 1) FC(h1B, 64, t - 2, sub >= 4, sub - 4);

        // ---- C_B: GEMM0_B(t) + GEMM1_B(t-1), publish, release ----
        GEMM0(h0B, xbB, c0B, gxr(1, 0, pc));
        if (t > 0) GEMM1(h0B, h1B, c1B, gxr(1, 1, pp));
        RELEASE(cB);

        // ---- S_A: spin for A's releases of iter t (covered by S_B + C_B) ----
        SPIN(cA, 8u * (unsigned)(t + 1));
        FILL(h0A, gxr(0, 0, pc));                 // h0A(t)
        if (t > 0) FILL(h1A, gxr(0, 1, pp));      // h1A(t-1)
        if (t + 1 < T_STEPS) XSTAGE(xbA, xa0, xa1);
        __syncthreads();
        if (t > 0) FC(h1A, 0, t - 1, sub < 4, sub);
    }

    // ---- epilogue: finish GEMM1(255) for both streams, emit remaining FC ----
    GEMM1(h0A, h1A, c1A, gxr(0, 1, 1));            // gates1_A(255), parity 255&1=1
    RELEASE(cA);                                   // cA -> 8*257
    SPIN(cB, 8u * 256u);
    FILL(h0B, gxr(1, 0, 1));                       // h0B(255)
    FILL(h1B, gxr(1, 1, 0));                       // h1B(254), parity 254&1=0
    __syncthreads();
    FC(h1B, 64, 254, sub >= 4, sub - 4);
    GEMM1(h0B, h1B, c1B, gxr(1, 1, 1));            // gates1_B(255)
    RELEASE(cB);                                   // cB -> 8*257
    SPIN(cA, 8u * 257u);
    FILL(h1A, gxr(0, 1, 1));                       // h1A(255)
    __syncthreads();
    FC(h1A, 0, 255, sub < 4, sub);
    SPIN(cB, 8u * 257u);
    FILL(h1B, gxr(1, 1, 1));                       // h1B(255)
    __syncthreads();
    FC(h1B, 64, 255, sub >= 4, sub - 4);
}

extern "C" void kernel_launch(void* const* d_in, const int* in_sizes, int n_in,
                              void* d_out, int out_size, void* d_ws, size_t ws_size,
                              hipStream_t stream)
{
    const float* x    = (const float*)d_in[0];
    const float* wih0 = (const float*)d_in[1];
    const float* whh0 = (const float*)d_in[2];
    const float* bih0 = (const float*)d_in[3];
    const float* bhh0 = (const float*)d_in[4];
    const float* wih1 = (const float*)d_in[5];
    const float* whh1 = (const float*)d_in[6];
    const float* bih1 = (const float*)d_in[7];
    const float* bhh1 = (const float*)d_in[8];
    const float* fcw  = (const float*)d_in[9];
    const float* fcb  = (const float*)d_in[10];

    u16* wsw      = (u16*)d_ws;
    float* biases = (float*)((char*)d_ws + WS_BIAS);
    u16* wsfc     = (u16*)((char*)d_ws + WS_FC);
    u16* gxbase   = (u16*)((char*)d_ws + WS_GX);
    unsigned* cnt = (unsigned*)((char*)d_ws + WS_CNT);

    prep_kernel<<<419, 256, 0, stream>>>(wih0, whh0, wih1, whh1,
                                         bih0, bhh0, bih1, bhh1, fcw,
                                         wsw, biases, wsfc, cnt);
    lstm_fused<<<NBLK, 256, 139264, stream>>>(x, wsw, biases, wsfc, fcb,
                                              (float*)d_out, gxbase, cnt);
}

// Round 14
// 6407.304 us; speedup vs baseline: 1.7259x; 1.1259x over previous
//
#include <hip/hip_runtime.h>

typedef unsigned short u16;
typedef _Float16 f16_t;
typedef f16_t f16x8 __attribute__((ext_vector_type(8)));
typedef float f32x4 __attribute__((ext_vector_type(4)));
typedef unsigned u32x4 __attribute__((ext_vector_type(4)));

#define T_STEPS 256
#define IN_DIM  5
#define NBLK    256

// d_ws byte layout:
//   WS_W    @ 0       : weight frags [32 slice][50 frag][64 lane][16B] = 1,638,400
//   WS_BIAS @ 1638400 : f32 bias0[1024], bias1[1024]                    (8 KB)
//   WS_FC   @ 1646592 : fc_w B-frags [8 ks][64 lane][16B]               (8 KB)
//   WS_GX   @ 1654784 : u16 gx[(stream*2+which)*2+parity][32 grp][8 sub][64 row][32 col]
//                       8 buffers x 1 MB = 8 MB
//   WS_CNT  @ 10043392: u32 cntA[1024], cntB[1024] (zeroed each launch by prep)
#define WS_BIAS 1638400
#define WS_FC   1646592
#define WS_GX   1654784
#define GXS     524288                  // u16 elements per (stream,which,parity) buffer
#define WS_CNT  (WS_GX + 8388608)

__device__ __forceinline__ float sigf(float x)  { return 1.0f / (1.0f + __expf(-x)); }
__device__ __forceinline__ float tanh_f(float x){ return 1.0f - 2.0f / (__expf(2.0f * x) + 1.0f); }

__global__ void prep_kernel(const float* __restrict__ wih0, const float* __restrict__ whh0,
                            const float* __restrict__ wih1, const float* __restrict__ whh1,
                            const float* __restrict__ bih0, const float* __restrict__ bhh0,
                            const float* __restrict__ bih1, const float* __restrict__ bhh1,
                            const float* __restrict__ fcw,
                            u16* __restrict__ wsw, float* __restrict__ biases,
                            u16* __restrict__ wsfc, unsigned* __restrict__ cnt)
{
    int j = blockIdx.x * blockDim.x + threadIdx.x;
    if (j < 102400) {
        // j = (slice*50 + f)*64 + lane ; slice = sub*4 + wv  (32 slices)
        int slice = j / 3200;
        int rem   = j - slice * 3200;
        int f     = rem >> 6;           // 0..49
        int lane  = rem & 63;
        int sub = slice >> 2, wv = slice & 3;
        int lrow = lane & 15;
        int kp = (lane >> 4) * 8;
        int nt, ks; bool g0;
        if (f < 18) { g0 = true;  nt = f / 9;  ks = f - nt * 9; }
        else        { int ff = f - 18; g0 = false; nt = ff >> 4; ks = ff & 15; }
        int wr = (nt * 2 + (lrow >> 3)) * 256 + sub * 32 + wv * 8 + (lrow & 7);
        u16 tmp[8];
#pragma unroll
        for (int e = 0; e < 8; ++e) {
            int k = kp + e;
            float v;
            if (g0) {
                v = (ks < 8) ? whh0[wr * 256 + ks * 32 + k]
                             : (k < IN_DIM ? wih0[wr * IN_DIM + k] : 0.0f);
            } else {
                v = (ks < 8) ? wih1[wr * 256 + ks * 32 + k]
                             : whh1[wr * 256 + (ks - 8) * 32 + k];
            }
            tmp[e] = __builtin_bit_cast(u16, (f16_t)v);
        }
        *(uint4*)(wsw + (size_t)j * 8) = *(uint4*)tmp;
    } else if (j < 103424) {
        int i = j - 102400;
        biases[i] = bih0[i] + bhh0[i];
    } else if (j < 104448) {
        int i = j - 103424;
        biases[1024 + i] = bih1[i] + bhh1[i];
    } else if (j < 104960) {
        // fc_w as MFMA B-fragments: B[k][n] = (n==0) ? fcw[k] : 0
        int q = j - 104448;
        int ks = q >> 6, lane = q & 63;
        u16 tmp[8];
#pragma unroll
        for (int e = 0; e < 8; ++e) {
            float v = ((lane & 15) == 0) ? fcw[ks * 32 + (lane >> 4) * 8 + e] : 0.0f;
            tmp[e] = __builtin_bit_cast(u16, (f16_t)v);
        }
        *(uint4*)(wsfc + (size_t)q * 8) = *(uint4*)tmp;
    } else if (j < 107008) {
        cnt[j - 104960] = 0u;
    }
}

__global__ __launch_bounds__(256, 1) void lstm_fused(
    const float* __restrict__ x, const u16* __restrict__ wsw,
    const float* __restrict__ biases, const u16* __restrict__ wsfc,
    const float* __restrict__ fcb_g, float* __restrict__ out,
    u16* __restrict__ gxbase, unsigned* __restrict__ cnt)
{
    extern __shared__ char smem[];
    char* h0A = smem;                  // [64 rows][512B] fp16, XOR-swizzled
    char* h1A = smem + 32768;
    char* xbA = smem + 65536;          // [64 rows][64B]
    char* h0B = smem + 69632;
    char* h1B = smem + 102400;
    char* xbB = smem + 135168;         // ends at 139264

    const int tid  = threadIdx.x;
    const int wv   = tid >> 6;
    const int lane = tid & 63;
    const int lrow = lane & 15;
    const int lkg  = lane >> 4;
    const int hf   = lrow >> 3;        // gate-half: 0 -> (i,g), 1 -> (f,o)
    const int cj   = lrow & 7;
    const int sub  = blockIdx.x >> 5;  // CU in group (0..7)
    const int grp  = blockIdx.x & 31;
    const int r0   = grp * 128;        // group owns 128 batch rows; A: +0..63, B: +64..127
    const int aswz = (lrow & 7) << 4;
    const int xswz = (lrow & 3) << 4;

    // ---- resident weights: 50 shard frags + 8 FC frags = 232 AGPRs/lane ----
    f16x8 w0[2][9], w1[2][16], wfc[8];
    const u16* wbase = wsw + (size_t)(sub * 4 + wv) * 25600;
#pragma unroll
    for (int nt = 0; nt < 2; ++nt)
#pragma unroll
        for (int ks = 0; ks < 9; ++ks) {
            w0[nt][ks] = *(const f16x8*)(wbase + (nt * 9 + ks) * 512 + lane * 8);
            asm volatile("" : "+a"(w0[nt][ks]));
            __builtin_amdgcn_sched_barrier(0);
        }
#pragma unroll
    for (int nt = 0; nt < 2; ++nt)
#pragma unroll
        for (int ks = 0; ks < 16; ++ks) {
            w1[nt][ks] = *(const f16x8*)(wbase + (18 + nt * 16 + ks) * 512 + lane * 8);
            asm volatile("" : "+a"(w1[nt][ks]));
            __builtin_amdgcn_sched_barrier(0);
        }
#pragma unroll
    for (int ks = 0; ks < 8; ++ks) {
        wfc[ks] = *(const f16x8*)(wsfc + ks * 512 + lane * 8);
        asm volatile("" : "+a"(wfc[ks]));
        __builtin_amdgcn_sched_barrier(0);
    }

    float b0[2], b1[2];
#pragma unroll
    for (int nt = 0; nt < 2; ++nt) {
        int wr = (nt * 2 + hf) * 256 + sub * 32 + wv * 8 + cj;
        b0[nt] = biases[wr];
        b1[nt] = biases[1024 + wr];
    }
    const float fcb = fcb_g[0];

    unsigned* cA = cnt + grp * 16;
    unsigned* cB = cnt + 1024 + grp * 16;

    auto gxr = [&](int stream, int which, int parity) -> u16* {
        return gxbase + (size_t)((stream * 2 + which) * 2 + parity) * GXS + grp * 16384;
    };

    // zero all LDS
    for (int i = tid; i < 139264 / 4; i += 256) ((unsigned*)smem)[i] = 0u;
    __syncthreads();
    // stage xA(0)
    {
        int i0 = tid, i1 = tid + 256;
        if (i0 < 320) { int row = i0 / 5, k = i0 - row * 5;
            float v = x[((size_t)(r0 + row) * T_STEPS + 0) * IN_DIM + k];
            *(u16*)(xbA + row * 64 + ((2 * k) ^ ((row & 3) << 4))) = __builtin_bit_cast(u16, (f16_t)v); }
        if (i1 < 320) { int row = i1 / 5, k = i1 - row * 5;
            float v = x[((size_t)(r0 + row) * T_STEPS + 0) * IN_DIM + k];
            *(u16*)(xbA + row * 64 + ((2 * k) ^ ((row & 3) << 4))) = __builtin_bit_cast(u16, (f16_t)v); }
    }
    __syncthreads();

    float c0A[4][2] = {}, c1A[4][2] = {}, c0B[4][2] = {}, c1B[4][2] = {};

    // publish helper: thread holds h(rowb+0),h(rowb+1) for col wv*8+cj; pair with
    // lane^1 so each thread stores ONE u32 = 2 adjacent cols of a single row.
    // volatile store -> sc0 sc1 device-coherent, no cache fences needed anywhere.
    auto PUB = [&](u16* gxw, int mt, unsigned hv) {
        unsigned sh = __shfl_xor(hv, 1);
        int rowb = mt * 16 + lkg * 4 + hf * 2;
        unsigned word;
        if (cj & 1) { word = (sh >> 16) | (hv & 0xffff0000u); rowb += 1; }
        else        { word = (hv & 0xffffu) | (sh << 16); }
        int colp = wv * 8 + (cj & ~1);
        *(volatile unsigned*)((char*)gxw + sub * 4096 + rowb * 64 + colp * 2) = word;
    };

    auto GEMM0 = [&](const char* h0s, const char* xbs, float (&cs)[4][2], u16* gxw) {
#pragma unroll
        for (int mt = 0; mt < 4; ++mt) {
            f32x4 a0 = {}, a1 = {};
            const int arow = mt * 16 + lrow;
#pragma unroll
            for (int ks = 0; ks < 8; ++ks) {
                f16x8 a = *(const f16x8*)(h0s + arow * 512 + ((ks * 64 + lkg * 16) ^ aswz));
                a0 = __builtin_amdgcn_mfma_f32_16x16x32_f16(a, w0[0][ks], a0, 0, 0, 0);
                a1 = __builtin_amdgcn_mfma_f32_16x16x32_f16(a, w0[1][ks], a1, 0, 0, 0);
            }
            {
                f16x8 a = *(const f16x8*)(xbs + arow * 64 + ((lkg * 16) ^ xswz));
                a0 = __builtin_amdgcn_mfma_f32_16x16x32_f16(a, w0[0][8], a0, 0, 0, 0);
                a1 = __builtin_amdgcn_mfma_f32_16x16x32_f16(a, w0[1][8], a1, 0, 0, 0);
            }
#pragma unroll
            for (int r = 0; r < 4; ++r) { a0[r] += b0[0]; a1[r] += b0[1]; }
            float sA0 = __shfl_xor(hf ? a0[0] : a0[2], 8);
            float sA1 = __shfl_xor(hf ? a0[1] : a0[3], 8);
            float sB0 = __shfl_xor(hf ? a1[0] : a1[2], 8);
            float sB1 = __shfl_xor(hf ? a1[1] : a1[3], 8);
            unsigned hv = 0;
#pragma unroll
            for (int rr = 0; rr < 2; ++rr) {
                float sa = rr ? sA1 : sA0, sb = rr ? sB1 : sB0;
                float ig = hf ? sa : a0[rr];
                float fg = hf ? a0[2 + rr] : sa;
                float gg = hf ? sb : a1[rr];
                float og = hf ? a1[2 + rr] : sb;
                float c  = sigf(fg) * cs[mt][rr] + sigf(ig) * tanh_f(gg);
                cs[mt][rr] = c;
                float h  = sigf(og) * tanh_f(c);
                hv |= (unsigned)__builtin_bit_cast(u16, (f16_t)h) << (16 * rr);
            }
            PUB(gxw, mt, hv);
        }
    };
    auto GEMM1 = [&](const char* h0s, const char* h1s, float (&cs)[4][2], u16* gxw) {
#pragma unroll
        for (int mt = 0; mt < 4; ++mt) {
            f32x4 a0 = {}, a1 = {};
            const int arow = mt * 16 + lrow;
#pragma unroll
            for (int ks = 0; ks < 8; ++ks) {
                f16x8 a = *(const f16x8*)(h0s + arow * 512 + ((ks * 64 + lkg * 16) ^ aswz));
                a0 = __builtin_amdgcn_mfma_f32_16x16x32_f16(a, w1[0][ks], a0, 0, 0, 0);
                a1 = __builtin_amdgcn_mfma_f32_16x16x32_f16(a, w1[1][ks], a1, 0, 0, 0);
            }
#pragma unroll
            for (int ks = 0; ks < 8; ++ks) {
                f16x8 a = *(const f16x8*)(h1s + arow * 512 + ((ks * 64 + lkg * 16) ^ aswz));
                a0 = __builtin_amdgcn_mfma_f32_16x16x32_f16(a, w1[0][8 + ks], a0, 0, 0, 0);
                a1 = __builtin_amdgcn_mfma_f32_16x16x32_f16(a, w1[1][8 + ks], a1, 0, 0, 0);
            }
#pragma unroll
            for (int r = 0; r < 4; ++r) { a0[r] += b1[0]; a1[r] += b1[1]; }
            float sA0 = __shfl_xor(hf ? a0[0] : a0[2], 8);
            float sA1 = __shfl_xor(hf ? a0[1] : a0[3], 8);
            float sB0 = __shfl_xor(hf ? a1[0] : a1[2], 8);
            float sB1 = __shfl_xor(hf ? a1[1] : a1[3], 8);
            unsigned hv = 0;
#pragma unroll
            for (int rr = 0; rr < 2; ++rr) {
                float sa = rr ? sA1 : sA0, sb = rr ? sB1 : sB0;
                float ig = hf ? sa : a0[rr];
                float fg = hf ? a0[2 + rr] : sa;
                float gg = hf ? sb : a1[rr];
                float og = hf ? a1[2 + rr] : sb;
                float c  = sigf(fg) * cs[mt][rr] + sigf(ig) * tanh_f(gg);
                cs[mt][rr] = c;
                float h  = sigf(og) * tanh_f(c);
                hv |= (unsigned)__builtin_bit_cast(u16, (f16_t)h) << (16 * rr);
            }
            PUB(gxw, mt, hv);
        }
    };
    // relaxed-only handshake: __syncthreads drains vmcnt (volatile stores are at
    // the device coherence point once retired), then one relaxed RMW. No release
    // fence -> no buffer_wbl2; no acquire fence -> no buffer_inv.
    auto RELEASE = [&](unsigned* p) {
        __syncthreads();
        if (tid == 0)
            __hip_atomic_fetch_add(p, 1u, __ATOMIC_RELAXED, __HIP_MEMORY_SCOPE_AGENT);
    };
    auto SPIN = [&](unsigned* p, unsigned tgt) {
        if (tid == 0) {
            while (__hip_atomic_load(p, __ATOMIC_RELAXED, __HIP_MEMORY_SCOPE_AGENT) < tgt)
                __builtin_amdgcn_s_sleep(1);
        }
        __syncthreads();
    };
    // fill: device-coherent dwordx4 loads (sc0 sc1 bypass stale caches), explicit
    // vmcnt drain + sched_barrier (rule #18), then swizzled LDS writes.
    auto FILL = [&](char* dst, const u16* src) {
        u32x4 q[8];
        const char* sb = (const char*)src;
        const int row = tid & 63;
#pragma unroll
        for (int ss = 0; ss < 2; ++ss) {
            int s2 = (tid >> 6) * 2 + ss;
            const char* sp = sb + s2 * 4096 + row * 64;
#pragma unroll
            for (int j = 0; j < 4; ++j)
                asm volatile("global_load_dwordx4 %0, %1, off sc0 sc1"
                             : "=&v"(q[ss * 4 + j]) : "v"(sp + j * 16));
        }
        asm volatile("s_waitcnt vmcnt(0)" ::: "memory");
        __builtin_amdgcn_sched_barrier(0);
        const int sw = (row & 7) << 4;
#pragma unroll
        for (int ss = 0; ss < 2; ++ss) {
            int s2 = (tid >> 6) * 2 + ss;
#pragma unroll
            for (int j = 0; j < 4; ++j)
                *(u32x4*)(dst + row * 512 + ((s2 * 64 + j * 16) ^ sw)) = q[ss * 4 + j];
        }
    };
    auto XLOAD = [&](int strOff, int tt, float& v0, float& v1) {
        v0 = 0.f; v1 = 0.f;
        int i0 = tid, i1 = tid + 256;
        if (i0 < 320) { int row = i0 / 5, k = i0 - row * 5;
            v0 = x[((size_t)(r0 + strOff + row) * T_STEPS + tt) * IN_DIM + k]; }
        if (i1 < 320) { int row = i1 / 5, k = i1 - row * 5;
            v1 = x[((size_t)(r0 + strOff + row) * T_STEPS + tt) * IN_DIM + k]; }
    };
    auto XSTAGE = [&](char* xbs, float v0, float v1) {
        int i0 = tid, i1 = tid + 256;
        if (i0 < 320) { int row = i0 / 5, k = i0 - row * 5;
            *(u16*)(xbs + row * 64 + ((2 * k) ^ ((row & 3) << 4))) = __builtin_bit_cast(u16, (f16_t)v0); }
        if (i1 < 320) { int row = i1 / 5, k = i1 - row * 5;
            *(u16*)(xbs + row * 64 + ((2 * k) ^ ((row & 3) << 4))) = __builtin_bit_cast(u16, (f16_t)v1); }
    };
    auto FC = [&](const char* h1s, int strOff, int tIdx, bool mine, int sub4) {
        if (wv == 0 && mine) {
            f32x4 acc = {};
            const int arow = sub4 * 16 + lrow;
#pragma unroll
            for (int ks = 0; ks < 8; ++ks) {
                f16x8 a = *(const f16x8*)(h1s + arow * 512 + ((ks * 64 + lkg * 16) ^ aswz));
                acc = __builtin_amdgcn_mfma_f32_16x16x32_f16(a, wfc[ks], acc, 0, 0, 0);
            }
            if (lrow == 0) {
#pragma unroll
                for (int r = 0; r < 4; ++r)
                    out[(size_t)(r0 + strOff + sub4 * 16 + lkg * 4 + r) * T_STEPS + tIdx] = acc[r] + fcb;
            }
        }
    };

#pragma unroll 1
    for (int t = 0; t < T_STEPS; ++t) {
        const int pc = t & 1, pp = (t - 1) & 1;

        float xa0, xa1, xbv0, xbv1;
        if (t + 1 < T_STEPS) { XLOAD(0, t + 1, xa0, xa1); } else { xa0 = 0.f; xa1 = 0.f; }
        XLOAD(64, t, xbv0, xbv1);

        // ---- C_A: GEMM0_A(t) + GEMM1_A(t-1), publish, release ----
        GEMM0(h0A, xbA, c0A, gxr(0, 0, pc));
        if (t > 0) GEMM1(h0A, h1A, c1A, gxr(0, 1, pp));
        RELEASE(cA);

        // ---- S_B: spin for B's releases of iter t-1 (covered by C_A) ----
        SPIN(cB, 8u * (unsigned)t);
        if (t > 0) FILL(h0B, gxr(1, 0, pp));      // h0B(t-1)
        if (t > 1) FILL(h1B, gxr(1, 1, pc));      // h1B(t-2): parity (t-2)&1 == t&1
        XSTAGE(xbB, xbv0, xbv1);                  // xB(t)
        __syncthreads();
        if (t > 1) FC(h1B, 64, t - 2, sub >= 4, sub - 4);

        // ---- C_B: GEMM0_B(t) + GEMM1_B(t-1), publish, release ----
        GEMM0(h0B, xbB, c0B, gxr(1, 0, pc));
        if (t > 0) GEMM1(h0B, h1B, c1B, gxr(1, 1, pp));
        RELEASE(cB);

        // ---- S_A: spin for A's releases of iter t (covered by S_B + C_B) ----
        SPIN(cA, 8u * (unsigned)(t + 1));
        FILL(h0A, gxr(0, 0, pc));                 // h0A(t)
        if (t > 0) FILL(h1A, gxr(0, 1, pp));      // h1A(t-1)
        if (t + 1 < T_STEPS) XSTAGE(xbA, xa0, xa1);
        __syncthreads();
        if (t > 0) FC(h1A, 0, t - 1, sub < 4, sub);
    }

    // ---- epilogue: finish GEMM1(255) for both streams, emit remaining FC ----
    GEMM1(h0A, h1A, c1A, gxr(0, 1, 1));            // gates1_A(255)
    RELEASE(cA);                                   // cA -> 8*257
    SPIN(cB, 8u * 256u);
    FILL(h0B, gxr(1, 0, 1));                       // h0B(255)
    FILL(h1B, gxr(1, 1, 0));                       // h1B(254)
    __syncthreads();
    FC(h1B, 64, 254, sub >= 4, sub - 4);
    GEMM1(h0B, h1B, c1B, gxr(1, 1, 1));            // gates1_B(255)
    RELEASE(cB);                                   // cB -> 8*257
    SPIN(cA, 8u * 257u);
    FILL(h1A, gxr(0, 1, 1));                       // h1A(255)
    __syncthreads();
    FC(h1A, 0, 255, sub < 4, sub);
    SPIN(cB, 8u * 257u);
    FILL(h1B, gxr(1, 1, 1));                       // h1B(255)
    __syncthreads();
    FC(h1B, 64, 255, sub >= 4, sub - 4);
}

extern "C" void kernel_launch(void* const* d_in, const int* in_sizes, int n_in,
                              void* d_out, int out_size, void* d_ws, size_t ws_size,
                              hipStream_t stream)
{
    const float* x    = (const float*)d_in[0];
    const float* wih0 = (const float*)d_in[1];
    const float* whh0 = (const float*)d_in[2];
    const float* bih0 = (const float*)d_in[3];
    const float* bhh0 = (const float*)d_in[4];
    const float* wih1 = (const float*)d_in[5];
    const float* whh1 = (const float*)d_in[6];
    const float* bih1 = (const float*)d_in[7];
    const float* bhh1 = (const float*)d_in[8];
    const float* fcw  = (const float*)d_in[9];
    const float* fcb  = (const float*)d_in[10];

    u16* wsw      = (u16*)d_ws;
    float* biases = (float*)((char*)d_ws + WS_BIAS);
    u16* wsfc     = (u16*)((char*)d_ws + WS_FC);
    u16* gxbase   = (u16*)((char*)d_ws + WS_GX);
    unsigned* cnt = (unsigned*)((char*)d_ws + WS_CNT);

    prep_kernel<<<419, 256, 0, stream>>>(wih0, whh0, wih1, whh1,
                                         bih0, bhh0, bih1, bhh1, fcw,
                                         wsw, biases, wsfc, cnt);
    lstm_fused<<<NBLK, 256, 139264, stream>>>(x, wsw, biases, wsfc, fcb,
                                              (float*)d_out, gxbase, cnt);
}

// Round 15
// 5714.583 us; speedup vs baseline: 1.9352x; 1.1212x over previous
//
#include <hip/hip_runtime.h>

typedef unsigned short u16;
typedef _Float16 f16_t;
typedef f16_t f16x8 __attribute__((ext_vector_type(8)));
typedef float f32x4 __attribute__((ext_vector_type(4)));
typedef unsigned u32x4 __attribute__((ext_vector_type(4)));

#define T_STEPS 256
#define IN_DIM  5
#define NBLK    256

// d_ws byte layout:
//   WS_W    @ 0       : weight frags [32 slice][50 frag][64 lane][16B] = 1,638,400
//   WS_BIAS @ 1638400 : f32 bias0[1024], bias1[1024]                    (8 KB)
//   WS_FC   @ 1646592 : fc_w B-frags [8 ks][64 lane][16B]               (8 KB)
//   WS_GX   @ 1654784 : u16 gx[(stream*2+which)*2+parity][32 grp][8 sub][64 row][32 col]
//                       8 buffers x 1 MB = 8 MB
//   WS_CNT  @ 10043392: u32 cntA[1024], cntB[1024] (zeroed each launch by prep)
#define WS_BIAS 1638400
#define WS_FC   1646592
#define WS_GX   1654784
#define GXS     524288                  // u16 elements per (stream,which,parity) buffer
#define WS_CNT  (WS_GX + 8388608)

__device__ __forceinline__ float sigf(float x)  { return 1.0f / (1.0f + __expf(-x)); }
__device__ __forceinline__ float tanh_f(float x){ return 1.0f - 2.0f / (__expf(2.0f * x) + 1.0f); }

__global__ void prep_kernel(const float* __restrict__ wih0, const float* __restrict__ whh0,
                            const float* __restrict__ wih1, const float* __restrict__ whh1,
                            const float* __restrict__ bih0, const float* __restrict__ bhh0,
                            const float* __restrict__ bih1, const float* __restrict__ bhh1,
                            const float* __restrict__ fcw,
                            u16* __restrict__ wsw, float* __restrict__ biases,
                            u16* __restrict__ wsfc, unsigned* __restrict__ cnt)
{
    int j = blockIdx.x * blockDim.x + threadIdx.x;
    if (j < 102400) {
        // j = (slice*50 + f)*64 + lane ; slice = sub*4 + wv  (32 slices)
        int slice = j / 3200;
        int rem   = j - slice * 3200;
        int f     = rem >> 6;           // 0..49
        int lane  = rem & 63;
        int sub = slice >> 2, wv = slice & 3;
        int lrow = lane & 15;
        int kp = (lane >> 4) * 8;
        int nt, ks; bool g0;
        if (f < 18) { g0 = true;  nt = f / 9;  ks = f - nt * 9; }
        else        { int ff = f - 18; g0 = false; nt = ff >> 4; ks = ff & 15; }
        int wr = (nt * 2 + (lrow >> 3)) * 256 + sub * 32 + wv * 8 + (lrow & 7);
        u16 tmp[8];
#pragma unroll
        for (int e = 0; e < 8; ++e) {
            int k = kp + e;
            float v;
            if (g0) {
                v = (ks < 8) ? whh0[wr * 256 + ks * 32 + k]
                             : (k < IN_DIM ? wih0[wr * IN_DIM + k] : 0.0f);
            } else {
                v = (ks < 8) ? wih1[wr * 256 + ks * 32 + k]
                             : whh1[wr * 256 + (ks - 8) * 32 + k];
            }
            tmp[e] = __builtin_bit_cast(u16, (f16_t)v);
        }
        *(uint4*)(wsw + (size_t)j * 8) = *(uint4*)tmp;
    } else if (j < 103424) {
        int i = j - 102400;
        biases[i] = bih0[i] + bhh0[i];
    } else if (j < 104448) {
        int i = j - 103424;
        biases[1024 + i] = bih1[i] + bhh1[i];
    } else if (j < 104960) {
        // fc_w as MFMA B-fragments: B[k][n] = (n==0) ? fcw[k] : 0
        int q = j - 104448;
        int ks = q >> 6, lane = q & 63;
        u16 tmp[8];
#pragma unroll
        for (int e = 0; e < 8; ++e) {
            float v = ((lane & 15) == 0) ? fcw[ks * 32 + (lane >> 4) * 8 + e] : 0.0f;
            tmp[e] = __builtin_bit_cast(u16, (f16_t)v);
        }
        *(uint4*)(wsfc + (size_t)q * 8) = *(uint4*)tmp;
    } else if (j < 107008) {
        cnt[j - 104960] = 0u;
    }
}

__global__ __launch_bounds__(256, 1) void lstm_fused(
    const float* __restrict__ x, const u16* __restrict__ wsw,
    const float* __restrict__ biases, const u16* __restrict__ wsfc,
    const float* __restrict__ fcb_g, float* __restrict__ out,
    u16* __restrict__ gxbase, unsigned* __restrict__ cnt)
{
    extern __shared__ char smem[];
    char* h0A = smem;                  // [64 rows][512B] fp16, XOR-swizzled
    char* h1A = smem + 32768;
    char* xbA = smem + 65536;          // [64 rows][64B]
    char* h0B = smem + 69632;
    char* h1B = smem + 102400;
    char* xbB = smem + 135168;         // ends at 139264

    const int tid  = threadIdx.x;
    const int wv   = tid >> 6;
    const int lane = tid & 63;
    const int lrow = lane & 15;
    const int lkg  = lane >> 4;
    const int hf   = lrow >> 3;        // gate-half: 0 -> (i,g), 1 -> (f,o)
    const int cj   = lrow & 7;
    const int sub  = blockIdx.x >> 5;  // CU in group (0..7)
    const int grp  = blockIdx.x & 31;
    const int r0   = grp * 128;        // group owns 128 batch rows; A: +0..63, B: +64..127
    const int aswz = (lrow & 7) << 4;
    const int xswz = (lrow & 3) << 4;

    // ---- resident weights: 50 shard frags + 8 FC frags = 232 AGPRs/lane ----
    f16x8 w0[2][9], w1[2][16], wfc[8];
    const u16* wbase = wsw + (size_t)(sub * 4 + wv) * 25600;
#pragma unroll
    for (int nt = 0; nt < 2; ++nt)
#pragma unroll
        for (int ks = 0; ks < 9; ++ks) {
            w0[nt][ks] = *(const f16x8*)(wbase + (nt * 9 + ks) * 512 + lane * 8);
            asm volatile("" : "+a"(w0[nt][ks]));
            __builtin_amdgcn_sched_barrier(0);
        }
#pragma unroll
    for (int nt = 0; nt < 2; ++nt)
#pragma unroll
        for (int ks = 0; ks < 16; ++ks) {
            w1[nt][ks] = *(const f16x8*)(wbase + (18 + nt * 16 + ks) * 512 + lane * 8);
            asm volatile("" : "+a"(w1[nt][ks]));
            __builtin_amdgcn_sched_barrier(0);
        }
#pragma unroll
    for (int ks = 0; ks < 8; ++ks) {
        wfc[ks] = *(const f16x8*)(wsfc + ks * 512 + lane * 8);
        asm volatile("" : "+a"(wfc[ks]));
        __builtin_amdgcn_sched_barrier(0);
    }

    float b0[2], b1[2];
#pragma unroll
    for (int nt = 0; nt < 2; ++nt) {
        int wr = (nt * 2 + hf) * 256 + sub * 32 + wv * 8 + cj;
        b0[nt] = biases[wr];
        b1[nt] = biases[1024 + wr];
    }
    const float fcb = fcb_g[0];

    unsigned* cA = cnt + grp * 16;
    unsigned* cB = cnt + 1024 + grp * 16;

    auto gxr = [&](int stream, int which, int parity) -> u16* {
        return gxbase + (size_t)((stream * 2 + which) * 2 + parity) * GXS + grp * 16384;
    };

    // zero all LDS
    for (int i = tid; i < 139264 / 4; i += 256) ((unsigned*)smem)[i] = 0u;
    __syncthreads();
    // stage xA(0)
    {
        int i0 = tid, i1 = tid + 256;
        if (i0 < 320) { int row = i0 / 5, k = i0 - row * 5;
            float v = x[((size_t)(r0 + row) * T_STEPS + 0) * IN_DIM + k];
            *(u16*)(xbA + row * 64 + ((2 * k) ^ ((row & 3) << 4))) = __builtin_bit_cast(u16, (f16_t)v); }
        if (i1 < 320) { int row = i1 / 5, k = i1 - row * 5;
            float v = x[((size_t)(r0 + row) * T_STEPS + 0) * IN_DIM + k];
            *(u16*)(xbA + row * 64 + ((2 * k) ^ ((row & 3) << 4))) = __builtin_bit_cast(u16, (f16_t)v); }
    }
    __syncthreads();

    float c0A[4][2] = {}, c1A[4][2] = {}, c0B[4][2] = {}, c1B[4][2] = {};

    // publish helper: pair with lane^1 so each thread stores ONE u32 = 2 adjacent
    // cols of one row. volatile -> sc0 sc1 device-coherent stores.
    auto PUB = [&](u16* gxw, int mt, unsigned hv) {
        unsigned sh = __shfl_xor(hv, 1);
        int rowb = mt * 16 + lkg * 4 + hf * 2;
        unsigned word;
        if (cj & 1) { word = (sh >> 16) | (hv & 0xffff0000u); rowb += 1; }
        else        { word = (hv & 0xffffu) | (sh << 16); }
        int colp = wv * 8 + (cj & ~1);
        *(volatile unsigned*)((char*)gxw + sub * 4096 + rowb * 64 + colp * 2) = word;
    };

    auto GEMM0 = [&](const char* h0s, const char* xbs, float (&cs)[4][2], u16* gxw) {
#pragma unroll
        for (int mt = 0; mt < 4; ++mt) {
            f32x4 a0 = {}, a1 = {};
            const int arow = mt * 16 + lrow;
#pragma unroll
            for (int ks = 0; ks < 8; ++ks) {
                f16x8 a = *(const f16x8*)(h0s + arow * 512 + ((ks * 64 + lkg * 16) ^ aswz));
                a0 = __builtin_amdgcn_mfma_f32_16x16x32_f16(a, w0[0][ks], a0, 0, 0, 0);
                a1 = __builtin_amdgcn_mfma_f32_16x16x32_f16(a, w0[1][ks], a1, 0, 0, 0);
            }
            {
                f16x8 a = *(const f16x8*)(xbs + arow * 64 + ((lkg * 16) ^ xswz));
                a0 = __builtin_amdgcn_mfma_f32_16x16x32_f16(a, w0[0][8], a0, 0, 0, 0);
                a1 = __builtin_amdgcn_mfma_f32_16x16x32_f16(a, w0[1][8], a1, 0, 0, 0);
            }
#pragma unroll
            for (int r = 0; r < 4; ++r) { a0[r] += b0[0]; a1[r] += b0[1]; }
            float sA0 = __shfl_xor(hf ? a0[0] : a0[2], 8);
            float sA1 = __shfl_xor(hf ? a0[1] : a0[3], 8);
            float sB0 = __shfl_xor(hf ? a1[0] : a1[2], 8);
            float sB1 = __shfl_xor(hf ? a1[1] : a1[3], 8);
            unsigned hv = 0;
#pragma unroll
            for (int rr = 0; rr < 2; ++rr) {
                float sa = rr ? sA1 : sA0, sb = rr ? sB1 : sB0;
                float ig = hf ? sa : a0[rr];
                float fg = hf ? a0[2 + rr] : sa;
                float gg = hf ? sb : a1[rr];
                float og = hf ? a1[2 + rr] : sb;
                float c  = sigf(fg) * cs[mt][rr] + sigf(ig) * tanh_f(gg);
                cs[mt][rr] = c;
                float h  = sigf(og) * tanh_f(c);
                hv |= (unsigned)__builtin_bit_cast(u16, (f16_t)h) << (16 * rr);
            }
            PUB(gxw, mt, hv);
        }
    };
    auto GEMM1 = [&](const char* h0s, const char* h1s, float (&cs)[4][2], u16* gxw) {
#pragma unroll
        for (int mt = 0; mt < 4; ++mt) {
            f32x4 a0 = {}, a1 = {};
            const int arow = mt * 16 + lrow;
#pragma unroll
            for (int ks = 0; ks < 8; ++ks) {
                f16x8 a = *(const f16x8*)(h0s + arow * 512 + ((ks * 64 + lkg * 16) ^ aswz));
                a0 = __builtin_amdgcn_mfma_f32_16x16x32_f16(a, w1[0][ks], a0, 0, 0, 0);
                a1 = __builtin_amdgcn_mfma_f32_16x16x32_f16(a, w1[1][ks], a1, 0, 0, 0);
            }
#pragma unroll
            for (int ks = 0; ks < 8; ++ks) {
                f16x8 a = *(const f16x8*)(h1s + arow * 512 + ((ks * 64 + lkg * 16) ^ aswz));
                a0 = __builtin_amdgcn_mfma_f32_16x16x32_f16(a, w1[0][8 + ks], a0, 0, 0, 0);
                a1 = __builtin_amdgcn_mfma_f32_16x16x32_f16(a, w1[1][8 + ks], a1, 0, 0, 0);
            }
#pragma unroll
            for (int r = 0; r < 4; ++r) { a0[r] += b1[0]; a1[r] += b1[1]; }
            float sA0 = __shfl_xor(hf ? a0[0] : a0[2], 8);
            float sA1 = __shfl_xor(hf ? a0[1] : a0[3], 8);
            float sB0 = __shfl_xor(hf ? a1[0] : a1[2], 8);
            float sB1 = __shfl_xor(hf ? a1[1] : a1[3], 8);
            unsigned hv = 0;
#pragma unroll
            for (int rr = 0; rr < 2; ++rr) {
                float sa = rr ? sA1 : sA0, sb = rr ? sB1 : sB0;
                float ig = hf ? sa : a0[rr];
                float fg = hf ? a0[2 + rr] : sa;
                float gg = hf ? sb : a1[rr];
                float og = hf ? a1[2 + rr] : sb;
                float c  = sigf(fg) * cs[mt][rr] + sigf(ig) * tanh_f(gg);
                cs[mt][rr] = c;
                float h  = sigf(og) * tanh_f(c);
                hv |= (unsigned)__builtin_bit_cast(u16, (f16_t)h) << (16 * rr);
            }
            PUB(gxw, mt, hv);
        }
    };
    // release: MUST be called immediately after a __syncthreads() (which drains
    // every wave's vmcnt -> all this CU's volatile pubs are at the coherence
    // point). One relaxed RMW; zero extra drain cost.
    auto REL = [&](unsigned* p) {
        if (tid == 0)
            __hip_atomic_fetch_add(p, 1u, __ATOMIC_RELAXED, __HIP_MEMORY_SCOPE_AGENT);
    };
    auto SPIN = [&](unsigned* p, unsigned tgt) {
        if (tid == 0) {
            while (__hip_atomic_load(p, __ATOMIC_RELAXED, __HIP_MEMORY_SCOPE_AGENT) < tgt)
                __builtin_amdgcn_s_sleep(1);
        }
        __syncthreads();
    };
    // merged fill: issue up to 16 coherent dwordx4 loads, ONE vmcnt drain
    // (shared with any still-pending publish stores), then swizzled LDS writes.
    auto FILL2 = [&](char* d0, const u16* s0, bool e0,
                     char* d1, const u16* s1, bool e1) {
        u32x4 q0[8], q1[8];
        const int row = tid & 63;
        const int base = (tid >> 6) * 2;
#pragma unroll
        for (int ss = 0; ss < 2; ++ss) {
            int s2 = base + ss;
            if (e0) {
                const char* sp = (const char*)s0 + s2 * 4096 + row * 64;
#pragma unroll
                for (int j = 0; j < 4; ++j)
                    asm volatile("global_load_dwordx4 %0, %1, off sc0 sc1"
                                 : "=&v"(q0[ss * 4 + j]) : "v"(sp + j * 16));
            }
            if (e1) {
                const char* sp = (const char*)s1 + s2 * 4096 + row * 64;
#pragma unroll
                for (int j = 0; j < 4; ++j)
                    asm volatile("global_load_dwordx4 %0, %1, off sc0 sc1"
                                 : "=&v"(q1[ss * 4 + j]) : "v"(sp + j * 16));
            }
        }
        asm volatile("s_waitcnt vmcnt(0)" ::: "memory");
        __builtin_amdgcn_sched_barrier(0);
        const int sw = (row & 7) << 4;
#pragma unroll
        for (int ss = 0; ss < 2; ++ss) {
            int s2 = base + ss;
            if (e0) {
#pragma unroll
                for (int j = 0; j < 4; ++j)
                    *(u32x4*)(d0 + row * 512 + ((s2 * 64 + j * 16) ^ sw)) = q0[ss * 4 + j];
            }
            if (e1) {
#pragma unroll
                for (int j = 0; j < 4; ++j)
                    *(u32x4*)(d1 + row * 512 + ((s2 * 64 + j * 16) ^ sw)) = q1[ss * 4 + j];
            }
        }
    };
    auto XLOAD = [&](int strOff, int tt, float& v0, float& v1) {
        v0 = 0.f; v1 = 0.f;
        int i0 = tid, i1 = tid + 256;
        if (i0 < 320) { int row = i0 / 5, k = i0 - row * 5;
            v0 = x[((size_t)(r0 + strOff + row) * T_STEPS + tt) * IN_DIM + k]; }
        if (i1 < 320) { int row = i1 / 5, k = i1 - row * 5;
            v1 = x[((size_t)(r0 + strOff + row) * T_STEPS + tt) * IN_DIM + k]; }
    };
    auto XSTAGE = [&](char* xbs, float v0, float v1) {
        int i0 = tid, i1 = tid + 256;
        if (i0 < 320) { int row = i0 / 5, k = i0 - row * 5;
            *(u16*)(xbs + row * 64 + ((2 * k) ^ ((row & 3) << 4))) = __builtin_bit_cast(u16, (f16_t)v0); }
        if (i1 < 320) { int row = i1 / 5, k = i1 - row * 5;
            *(u16*)(xbs + row * 64 + ((2 * k) ^ ((row & 3) << 4))) = __builtin_bit_cast(u16, (f16_t)v1); }
    };
    auto FC = [&](const char* h1s, int strOff, int tIdx, bool mine, int sub4) {
        if (wv == 0 && mine) {
            f32x4 acc = {};
            const int arow = sub4 * 16 + lrow;
#pragma unroll
            for (int ks = 0; ks < 8; ++ks) {
                f16x8 a = *(const f16x8*)(h1s + arow * 512 + ((ks * 64 + lkg * 16) ^ aswz));
                acc = __builtin_amdgcn_mfma_f32_16x16x32_f16(a, wfc[ks], acc, 0, 0, 0);
            }
            if (lrow == 0) {
#pragma unroll
                for (int r = 0; r < 4; ++r)
                    out[(size_t)(r0 + strOff + sub4 * 16 + lkg * 4 + r) * T_STEPS + tIdx] = acc[r] + fcb;
            }
        }
    };

#pragma unroll 1
    for (int t = 0; t < T_STEPS; ++t) {
        const int pc = t & 1, pp = (t - 1) & 1;

        float xa0, xa1, xbv0, xbv1;
        if (t + 1 < T_STEPS) { XLOAD(0, t + 1, xa0, xa1); } else { xa0 = 0.f; xa1 = 0.f; }
        XLOAD(64, t, xbv0, xbv1);

        // ---- C_A: GEMM0_A(t) + GEMM1_A(t-1), publish only (no waits) ----
        GEMM0(h0A, xbA, c0A, gxr(0, 0, pc));
        if (t > 0) GEMM1(h0A, h1A, c1A, gxr(0, 1, pp));

        // ---- S_B: spin cB(t-1); merged fills; barrier; release cA(t) ----
        SPIN(cB, 8u * (unsigned)t);
        FILL2(h0B, gxr(1, 0, pp), t > 0,          // h0B(t-1)
              h1B, gxr(1, 1, pc), t > 1);         // h1B(t-2): (t-2)&1 == t&1
        XSTAGE(xbB, xbv0, xbv1);                  // xB(t)
        __syncthreads();                          // drains C_A pubs + LDS writes
        REL(cA);
        if (t > 1) FC(h1B, 64, t - 2, sub >= 4, sub - 4);

        // ---- C_B: GEMM0_B(t) + GEMM1_B(t-1), publish only ----
        GEMM0(h0B, xbB, c0B, gxr(1, 0, pc));
        if (t > 0) GEMM1(h0B, h1B, c1B, gxr(1, 1, pp));

        // ---- S_A: spin cA(t); merged fills; barrier; release cB(t) ----
        SPIN(cA, 8u * (unsigned)(t + 1));
        FILL2(h0A, gxr(0, 0, pc), true,           // h0A(t)
              h1A, gxr(0, 1, pp), t > 0);         // h1A(t-1)
        if (t + 1 < T_STEPS) XSTAGE(xbA, xa0, xa1);
        __syncthreads();                          // drains C_B pubs + LDS writes
        REL(cB);
        if (t > 0) FC(h1A, 0, t - 1, sub < 4, sub);
    }

    // ---- epilogue: finish GEMM1(255) for both streams, emit remaining FC ----
    GEMM1(h0A, h1A, c1A, gxr(0, 1, 1));            // pub h1A(255)
    SPIN(cB, 8u * 256u);                           // everyone's S_A(255) done
    FILL2(h0B, gxr(1, 0, 1), true,                 // h0B(255)
          h1B, gxr(1, 1, 0), true);                // h1B(254)
    __syncthreads();
    REL(cA);                                       // cA -> 8*257
    FC(h1B, 64, 254, sub >= 4, sub - 4);
    GEMM1(h0B, h1B, c1B, gxr(1, 1, 1));            // pub h1B(255)
    SPIN(cA, 8u * 257u);
    FILL2(h1A, gxr(0, 1, 1), true, h1A, gxr(0, 1, 1), false);  // h1A(255)
    __syncthreads();
    REL(cB);                                       // cB -> 8*257
    FC(h1A, 0, 255, sub < 4, sub);
    SPIN(cB, 8u * 257u);
    FILL2(h1B, gxr(1, 1, 1), true, h1B, gxr(1, 1, 1), false);  // h1B(255)
    __syncthreads();
    FC(h1B, 64, 255, sub >= 4, sub - 4);
}

extern "C" void kernel_launch(void* const* d_in, const int* in_sizes, int n_in,
                              void* d_out, int out_size, void* d_ws, size_t ws_size,
                              hipStream_t stream)
{
    const float* x    = (const float*)d_in[0];
    const float* wih0 = (const float*)d_in[1];
    const float* whh0 = (const float*)d_in[2];
    const float* bih0 = (const float*)d_in[3];
    const float* bhh0 = (const float*)d_in[4];
    const float* wih1 = (const float*)d_in[5];
    const float* whh1 = (const float*)d_in[6];
    const float* bih1 = (const float*)d_in[7];
    const float* bhh1 = (const float*)d_in[8];
    const float* fcw  = (const float*)d_in[9];
    const float* fcb  = (const float*)d_in[10];

    u16* wsw      = (u16*)d_ws;
    float* biases = (float*)((char*)d_ws + WS_BIAS);
    u16* wsfc     = (u16*)((char*)d_ws + WS_FC);
    u16* gxbase   = (u16*)((char*)d_ws + WS_GX);
    unsigned* cnt = (unsigned*)((char*)d_ws + WS_CNT);

    prep_kernel<<<419, 256, 0, stream>>>(wih0, whh0, wih1, whh1,
                                         bih0, bhh0, bih1, bhh1, fcw,
                                         wsw, biases, wsfc, cnt);
    lstm_fused<<<NBLK, 256, 139264, stream>>>(x, wsw, biases, wsfc, fcb,
                                              (float*)d_out, gxbase, cnt);
}